// Round 1
// baseline (6487.743 us; speedup 1.0000x reference)
//
#include <hip/hip_runtime.h>
#include <hip/hip_bf16.h>

// Problem constants (from reference)
#define N_NODES 100000
#define N_EDGES 1600000
#define D_NODE 128
#define D_EDGE 64
#define D_MSG 128
#define K1 192   // NODE_DIM + EDGE_DIM
#define K2 256   // NODE_DIM + MSG_DIM
#define D_OUT 128

static __device__ __forceinline__ unsigned int f32_to_bf16_bits(float f) {
    unsigned int u = __float_as_uint(f);
    // round-to-nearest-even
    return (u + 0x7fffu + ((u >> 16) & 1u));
}

// ---------------------------------------------------------------------------
// Edge kernel: msg = relu([x_src, edge_emb] @ W_msg + b_msg); atomic scatter.
// 256 threads. Per iteration: 16 edges. thread t: edge eL = t>>4, out group
// og = t&15 (8 consecutive outputs og*8..og*8+7).
// LDS: W_msg as bf16 pairs (48KB) + input tile (12.8KB) = ~62KB -> 2 blk/CU.
// ---------------------------------------------------------------------------
__global__ __launch_bounds__(256) void edge_kernel(
    const float* __restrict__ node_emb, const int* __restrict__ src,
    const int* __restrict__ dst, const float* __restrict__ edge_emb,
    const float* __restrict__ W_msg, const float* __restrict__ b_msg,
    float* __restrict__ summed, float* __restrict__ counts)
{
    __shared__ unsigned int sW[K1][D_MSG / 2];   // bf16 pair per u32: 49152 B
    __shared__ float sIn[16][K1 + 8];            // padded stride 200: 12800 B
    __shared__ int sSrc[16];
    __shared__ int sDst[16];

    // Stage W_msg once per block as packed bf16 pairs (lo = out 2j, hi = 2j+1)
    for (int idx = threadIdx.x; idx < K1 * (D_MSG / 2); idx += 256) {
        int k = idx / (D_MSG / 2);
        int o2 = idx % (D_MSG / 2);
        unsigned int lo = f32_to_bf16_bits(W_msg[k * D_MSG + o2 * 2 + 0]) >> 16;
        unsigned int hi = f32_to_bf16_bits(W_msg[k * D_MSG + o2 * 2 + 1]) & 0xffff0000u;
        sW[k][o2] = lo | hi;
    }

    const int eL = threadIdx.x >> 4;
    const int og = threadIdx.x & 15;

    float bias[8];
#pragma unroll
    for (int j = 0; j < 8; ++j) bias[j] = b_msg[og * 8 + j];

    const int nTiles = N_EDGES / 16;  // 100000, exact
    for (int tile = blockIdx.x; tile < nTiles; tile += gridDim.x) {
        const int e0 = tile * 16;
        __syncthreads();  // protect sIn/sSrc/sDst reuse (also covers sW on iter 0)
        if (threadIdx.x < 16) {
            // clamp defensively (dtype surprise -> wrong numbers, not segfault)
            int s = src[e0 + threadIdx.x];
            int d = dst[e0 + threadIdx.x];
            sSrc[threadIdx.x] = min(max(s, 0), N_NODES - 1);
            sDst[threadIdx.x] = min(max(d, 0), N_NODES - 1);
        }
        __syncthreads();
        // Stage the 16x192 input tile: [x_src | edge_emb]
        for (int idx = threadIdx.x; idx < 16 * K1; idx += 256) {
            int e = idx / K1;
            int k = idx - e * K1;
            float v;
            if (k < D_NODE) v = node_emb[(long)sSrc[e] * D_NODE + k];
            else            v = edge_emb[(long)(e0 + e) * D_EDGE + (k - D_NODE)];
            sIn[e][k] = v;
        }
        __syncthreads();

        const float* __restrict__ inRow = &sIn[eL][0];
        float acc[8];
#pragma unroll
        for (int j = 0; j < 8; ++j) acc[j] = bias[j];

#pragma unroll 4
        for (int k = 0; k < K1; ++k) {
            float in = inRow[k];
#pragma unroll
            for (int j2 = 0; j2 < 4; ++j2) {
                unsigned int u = sW[k][og * 4 + j2];
                acc[2 * j2]     = fmaf(in, __uint_as_float(u << 16), acc[2 * j2]);
                acc[2 * j2 + 1] = fmaf(in, __uint_as_float(u & 0xffff0000u), acc[2 * j2 + 1]);
            }
        }

        const int d = sDst[eL];
        float* outp = summed + (long)d * D_MSG + og * 8;
#pragma unroll
        for (int j = 0; j < 8; ++j) {
            float m = acc[j] > 0.f ? acc[j] : 0.f;
            atomicAdd(outp + j, m);
        }
        if (og == 0) atomicAdd(&counts[d], 1.0f);
    }
}

// ---------------------------------------------------------------------------
// Node kernel: h = relu([node_emb, summed/max(cnt,1)] @ W_upd + b_upd)
// Each block owns one output half (64 outs) so bf16 W slice fits in 32KB LDS.
// 256 threads; 8 nodes per iteration; thread t: node nL = t>>5, outs
// (t&31)*2, (t&31)*2+1 within the half.
// ---------------------------------------------------------------------------
__global__ __launch_bounds__(256) void node_kernel(
    const float* __restrict__ node_emb, const float* __restrict__ summed,
    const float* __restrict__ counts, const float* __restrict__ W_upd,
    const float* __restrict__ b_upd, float* __restrict__ out)
{
    __shared__ unsigned int sW[K2][32];   // 256 x 32 u32 (bf16 pairs) = 32768 B
    __shared__ float sIn[8][K2 + 8];      // 8 x 264 x 4 = 8448 B
    __shared__ float sInv[8];

    const int half = blockIdx.x & 1;           // which 64-output half
    const int oBase = half * 64;

    for (int idx = threadIdx.x; idx < K2 * 32; idx += 256) {
        int k = idx >> 5;
        int j = idx & 31;
        int o = oBase + j * 2;
        unsigned int lo = f32_to_bf16_bits(W_upd[k * D_OUT + o]) >> 16;
        unsigned int hi = f32_to_bf16_bits(W_upd[k * D_OUT + o + 1]) & 0xffff0000u;
        sW[k][j] = lo | hi;
    }

    const int nL = threadIdx.x >> 5;
    const int j = threadIdx.x & 31;
    const float b0 = b_upd[oBase + j * 2];
    const float b1 = b_upd[oBase + j * 2 + 1];

    const int nTiles = N_NODES / 8;  // 12500, exact
    const int stride = gridDim.x >> 1;
    for (int tile = blockIdx.x >> 1; tile < nTiles; tile += stride) {
        const int n0 = tile * 8;
        __syncthreads();
        if (threadIdx.x < 8) {
            float c = counts[n0 + threadIdx.x];
            sInv[threadIdx.x] = 1.0f / fmaxf(c, 1.0f);
        }
        __syncthreads();
        for (int idx = threadIdx.x; idx < 8 * K2; idx += 256) {
            int nl = idx >> 8;
            int k = idx & 255;
            long n = n0 + nl;
            float v;
            if (k < D_NODE) v = node_emb[n * D_NODE + k];
            else            v = summed[n * D_MSG + (k - D_NODE)] * sInv[nl];
            sIn[nl][k] = v;
        }
        __syncthreads();

        const float* __restrict__ inRow = &sIn[nL][0];
        float a0 = b0, a1 = b1;
#pragma unroll 4
        for (int k = 0; k < K2; ++k) {
            float in = inRow[k];
            unsigned int u = sW[k][j];
            a0 = fmaf(in, __uint_as_float(u << 16), a0);
            a1 = fmaf(in, __uint_as_float(u & 0xffff0000u), a1);
        }

        long n = n0 + nL;
        float* op = out + n * D_OUT + oBase + j * 2;
        op[0] = fmaxf(a0, 0.f);
        op[1] = fmaxf(a1, 0.f);
    }
}

extern "C" void kernel_launch(void* const* d_in, const int* in_sizes, int n_in,
                              void* d_out, int out_size, void* d_ws, size_t ws_size,
                              hipStream_t stream) {
    const float* node_emb = (const float*)d_in[0];
    const int*   edge_idx = (const int*)d_in[1];   // [2, E] row-major, int32
    const float* edge_emb = (const float*)d_in[2];
    const float* W_msg    = (const float*)d_in[3];
    const float* b_msg    = (const float*)d_in[4];
    const float* W_upd    = (const float*)d_in[5];
    const float* b_upd    = (const float*)d_in[6];
    float* out = (float*)d_out;

    float* summed = (float*)d_ws;                        // [N, 128]
    float* cnts   = summed + (size_t)N_NODES * D_MSG;    // [N]

    // zero accumulators every call (harness does not re-poison between replays)
    size_t accBytes = ((size_t)N_NODES * D_MSG + N_NODES) * sizeof(float);
    hipMemsetAsync(d_ws, 0, accBytes, stream);

    const int* src = edge_idx;
    const int* dst = edge_idx + N_EDGES;

    edge_kernel<<<1024, 256, 0, stream>>>(node_emb, src, dst, edge_emb,
                                          W_msg, b_msg, summed, cnts);
    node_kernel<<<2048, 256, 0, stream>>>(node_emb, summed, cnts,
                                          W_upd, b_upd, out);
}

// Round 3
// 1258.179 us; speedup vs baseline: 5.1565x; 5.1565x over previous
//
#include <hip/hip_runtime.h>
#include <hip/hip_bf16.h>

#define N_NODES 100000
#define N_EDGES 1600000
#define D_NODE 128
#define D_EDGE 64
#define D_MSG 128
#define K1 192   // NODE_DIM + EDGE_DIM
#define K2 256   // NODE_DIM + MSG_DIM
#define D_OUT 128
#define NSB 98   // scan blocks: ceil(100000/1024)

using frag8 = __attribute__((ext_vector_type(8))) short;   // 8 bf16 (4 VGPRs)
using facc  = __attribute__((ext_vector_type(4))) float;   // 4 f32 acc

static __device__ __forceinline__ unsigned short f2bf(float f) {
    unsigned int u = __float_as_uint(f);
    u = u + 0x7fffu + ((u >> 16) & 1u);   // RNE
    return (unsigned short)(u >> 16);
}

union F8 { unsigned short s[8]; frag8 f; };

static __device__ __forceinline__ frag8 pack8(float4 a, float4 b) {
    F8 u;
    u.s[0] = f2bf(a.x); u.s[1] = f2bf(a.y); u.s[2] = f2bf(a.z); u.s[3] = f2bf(a.w);
    u.s[4] = f2bf(b.x); u.s[5] = f2bf(b.y); u.s[6] = f2bf(b.z); u.s[7] = f2bf(b.w);
    return u.f;
}

// ---------------------------------------------------------------------------
// Prep: W transposed to [out][k] bf16 in global ws.
// ---------------------------------------------------------------------------
__global__ void prep_kernel(const float* __restrict__ Wm, const float* __restrict__ Wu,
                            unsigned short* __restrict__ WtM, unsigned short* __restrict__ WtU) {
    int idx0 = blockIdx.x * blockDim.x + threadIdx.x;
    int stride = gridDim.x * blockDim.x;
    for (int idx = idx0; idx < 128 * K1; idx += stride) {
        int o = idx / K1, k = idx - o * K1;
        WtM[idx] = f2bf(Wm[k * D_MSG + o]);
    }
    for (int idx = idx0; idx < 128 * K2; idx += stride) {
        int o = idx >> 8, k = idx & 255;
        WtU[idx] = f2bf(Wu[k * D_OUT + o]);
    }
}

__global__ void hist_kernel(const int* __restrict__ dst, int* __restrict__ cnt) {
    int idx0 = blockIdx.x * blockDim.x + threadIdx.x;
    int stride = gridDim.x * blockDim.x;
    for (int e = idx0; e < N_EDGES; e += stride) {
        int d = min(max(dst[e], 0), N_NODES - 1);
        atomicAdd(&cnt[d], 1);
    }
}

__global__ __launch_bounds__(1024) void scan_blocks(const int* __restrict__ cnt,
                                                    int* __restrict__ base,
                                                    int* __restrict__ part) {
    __shared__ int sh[1024];
    int i = blockIdx.x * 1024 + threadIdx.x;
    int c = (i < N_NODES) ? cnt[i] : 0;
    sh[threadIdx.x] = c;
    __syncthreads();
    for (int s = 1; s < 1024; s <<= 1) {
        int t = (threadIdx.x >= s) ? sh[threadIdx.x - s] : 0;
        __syncthreads();
        sh[threadIdx.x] += t;
        __syncthreads();
    }
    if (i < N_NODES) base[i] = sh[threadIdx.x] - c;   // exclusive within block
    if (threadIdx.x == 1023) part[blockIdx.x] = sh[1023];
}

__global__ void scan_partials(int* __restrict__ part) {
    if (threadIdx.x == 0 && blockIdx.x == 0) {
        int run = 0;
        for (int b = 0; b < NSB; ++b) { int t = part[b]; part[b] = run; run += t; }
    }
}

__global__ __launch_bounds__(1024) void scan_add(int* __restrict__ base, const int* __restrict__ part) {
    int i = blockIdx.x * 1024 + threadIdx.x;
    if (i < N_NODES) base[i] += part[blockIdx.x];
}

__global__ void scatter_kernel(const int* __restrict__ dst, const int* __restrict__ base,
                               int* __restrict__ cursor, int* __restrict__ perm,
                               int* __restrict__ dstS) {
    int idx0 = blockIdx.x * blockDim.x + threadIdx.x;
    int stride = gridDim.x * blockDim.x;
    for (int e = idx0; e < N_EDGES; e += stride) {
        int d = min(max(dst[e], 0), N_NODES - 1);
        int pos = base[d] + atomicAdd(&cursor[d], 1);
        perm[pos] = e;
        dstS[pos] = d;
    }
}

// ---------------------------------------------------------------------------
// Fused message GEMM + mean-aggregate over dst-sorted edges.
// Lane owns one edge column (j=l&15) and 32 output rows. Segmented
// shuffle-reduce across 16 lanes; partials pre-divided by count; one
// atomicAdd burst per segment. ALL shuffles executed unconditionally
// (divergent shfl from inactive source lanes is UB on CDNA — round-2 bug).
// ---------------------------------------------------------------------------
__global__ __launch_bounds__(256) void msg_agg_kernel(
    const float* __restrict__ node_emb, const int* __restrict__ src,
    const float* __restrict__ edge_emb, const unsigned short* __restrict__ WtM,
    const float* __restrict__ b_msg, const int* __restrict__ perm,
    const int* __restrict__ dstS, const int* __restrict__ cnt,
    float* __restrict__ mean)
{
    __shared__ unsigned short sW[128 * K1];   // 49152 B, chunk-XOR-swizzled

    // stage Wt: chunk = 8 bf16 = 16B; swizzle chunk index by row&7 (T2)
    for (int idx = threadIdx.x; idx < 128 * 24; idx += 256) {
        int o = idx / 24, ch = idx % 24;
        int chs = ch ^ (o & 7);
        *(uint4*)&sW[o * K1 + chs * 8] = *(const uint4*)&WtM[o * K1 + ch * 8];
    }

    const int lane = threadIdx.x & 63;
    const int wav  = threadIdx.x >> 6;
    const int j = lane & 15;
    const int q = lane >> 4;

    float bias[32];
#pragma unroll
    for (int mt = 0; mt < 8; ++mt)
#pragma unroll
        for (int r = 0; r < 4; ++r) bias[mt * 4 + r] = b_msg[mt * 16 + q * 4 + r];
    __syncthreads();

    const int e0w = blockIdx.x * 256 + wav * 64;
    float carry[32];
    int carry_d = -1;

#pragma unroll 1
    for (int g = 0; g < 4; ++g) {
        const int e = e0w + g * 16 + j;
        const int p = perm[e];
        const int d = dstS[e];
        const int sp = min(max(src[p], 0), N_NODES - 1);
        const float invc = 1.0f / (float)cnt[d];

        // B fragments: 8 consecutive features of MY edge's input row per frag
        frag8 bfr[6];
        const float* nrow = node_emb + (size_t)sp * D_NODE;
#pragma unroll
        for (int kc = 0; kc < 4; ++kc) {
            float4 a = *(const float4*)&nrow[kc * 32 + q * 8];
            float4 c = *(const float4*)&nrow[kc * 32 + q * 8 + 4];
            bfr[kc] = pack8(a, c);
        }
        const float* erow = edge_emb + (size_t)p * D_EDGE;
#pragma unroll
        for (int kc = 0; kc < 2; ++kc) {
            float4 a = *(const float4*)&erow[kc * 32 + q * 8];
            float4 c = *(const float4*)&erow[kc * 32 + q * 8 + 4];
            bfr[4 + kc] = pack8(a, c);
        }

        facc acc[8];
#pragma unroll
        for (int mt = 0; mt < 8; ++mt) { facc z = {0.f, 0.f, 0.f, 0.f}; acc[mt] = z; }

#pragma unroll
        for (int mt = 0; mt < 8; ++mt) {
            const unsigned short* wrow = &sW[(mt * 16 + j) * K1];
            const int rs = j & 7;
#pragma unroll
            for (int kc = 0; kc < 6; ++kc) {
                int ch = kc * 4 + q;
                frag8 a = *(const frag8*)&wrow[(ch ^ rs) * 8];
                acc[mt] = __builtin_amdgcn_mfma_f32_16x16x32_bf16(a, bfr[kc], acc[mt], 0, 0, 0);
            }
        }

        // bias + relu + pre-divide by count
        float v[32];
#pragma unroll
        for (int mt = 0; mt < 8; ++mt)
#pragma unroll
            for (int r = 0; r < 4; ++r) {
                float t = acc[mt][r] + bias[mt * 4 + r];
                v[mt * 4 + r] = fmaxf(t, 0.f) * invc;
            }

        // segment ids over the 16 sorted edges (all shuffles unconditional)
        int dprev = __shfl_up(d, 1, 16);
        int head = (j == 0 || d != dprev) ? 1 : 0;
        int seg = head;
#pragma unroll
        for (int s = 1; s < 16; s <<= 1) { int t = __shfl_up(seg, s, 16); if (j >= s) seg += t; }
        // hoisted: every lane executes these shuffles (fix for round-2 UB)
        int sg1 = __shfl_up(seg, 1, 16);
        int sg2 = __shfl_up(seg, 2, 16);
        int sg4 = __shfl_up(seg, 4, 16);
        int sg8 = __shfl_up(seg, 8, 16);
        bool ok1 = (j >= 1) && (sg1 == seg);
        bool ok2 = (j >= 2) && (sg2 == seg);
        bool ok4 = (j >= 4) && (sg4 == seg);
        bool ok8 = (j >= 8) && (sg8 == seg);

        // segmented inclusive sum across lanes (shuffles unconditional)
#pragma unroll
        for (int i = 0; i < 32; ++i) { float t = __shfl_up(v[i], 1, 16); if (ok1) v[i] += t; }
#pragma unroll
        for (int i = 0; i < 32; ++i) { float t = __shfl_up(v[i], 2, 16); if (ok2) v[i] += t; }
#pragma unroll
        for (int i = 0; i < 32; ++i) { float t = __shfl_up(v[i], 4, 16); if (ok4) v[i] += t; }
#pragma unroll
        for (int i = 0; i < 32; ++i) { float t = __shfl_up(v[i], 8, 16); if (ok8) v[i] += t; }

        // carry handling from previous group in this wave's 64-edge run
        int d0 = __shfl(d, 0, 16);
        if (g > 0) {
            if (d0 != carry_d) {
                // previous run-tail segment closed at group boundary: flush it
                if (j == 0) {
                    float* mrow = mean + (size_t)carry_d * D_MSG;
#pragma unroll
                    for (int mt = 0; mt < 8; ++mt)
#pragma unroll
                        for (int r = 0; r < 4; ++r)
                            atomicAdd(&mrow[mt * 16 + q * 4 + r], carry[mt * 4 + r]);
                }
            } else if (seg == 1) {
#pragma unroll
                for (int i = 0; i < 32; ++i) v[i] += carry[i];
            }
        }

        // new carry = last segment's running partial (broadcast from lane 15)
#pragma unroll
        for (int i = 0; i < 32; ++i) carry[i] = __shfl(v[i], 15, 16);
        carry_d = __shfl(d, 15, 16);

        int dnext = __shfl_down(d, 1, 16);
        bool tail = (j < 15) ? (dnext != d) : (g == 3);
        if (tail) {
            float* mrow = mean + (size_t)d * D_MSG;
#pragma unroll
            for (int mt = 0; mt < 8; ++mt)
#pragma unroll
                for (int r = 0; r < 4; ++r)
                    atomicAdd(&mrow[mt * 16 + q * 4 + r], v[mt * 4 + r]);
        }
    }
}

// ---------------------------------------------------------------------------
// Node update GEMM: out = relu([node_emb | mean] @ W_upd + b).
// ---------------------------------------------------------------------------
__global__ __launch_bounds__(256) void node_kernel(
    const float* __restrict__ node_emb, const float* __restrict__ mean,
    const unsigned short* __restrict__ WtU, const float* __restrict__ b_upd,
    float* __restrict__ out)
{
    __shared__ unsigned short sW[128 * K2];   // 65536 B, chunk-XOR-swizzled

    for (int idx = threadIdx.x; idx < 128 * 32; idx += 256) {
        int o = idx >> 5, ch = idx & 31;
        int chs = ch ^ (o & 7);
        *(uint4*)&sW[o * K2 + chs * 8] = *(const uint4*)&WtU[o * K2 + ch * 8];
    }

    const int lane = threadIdx.x & 63;
    const int wav  = threadIdx.x >> 6;
    const int j = lane & 15;
    const int q = lane >> 4;

    float bias[32];
#pragma unroll
    for (int mt = 0; mt < 8; ++mt)
#pragma unroll
        for (int r = 0; r < 4; ++r) bias[mt * 4 + r] = b_upd[mt * 16 + q * 4 + r];
    __syncthreads();

    const int n0w = blockIdx.x * 256 + wav * 64;

#pragma unroll 1
    for (int g = 0; g < 4; ++g) {
        const int n = n0w + g * 16 + j;
        const bool valid = (n < N_NODES);
        const size_t nn = valid ? (size_t)n : 0;

        frag8 bfr[8];
        const float* nrow = node_emb + nn * D_NODE;
#pragma unroll
        for (int kc = 0; kc < 4; ++kc) {
            float4 a = *(const float4*)&nrow[kc * 32 + q * 8];
            float4 c = *(const float4*)&nrow[kc * 32 + q * 8 + 4];
            bfr[kc] = pack8(a, c);
        }
        const float* mrow = mean + nn * D_MSG;
#pragma unroll
        for (int kc = 0; kc < 4; ++kc) {
            float4 a = *(const float4*)&mrow[kc * 32 + q * 8];
            float4 c = *(const float4*)&mrow[kc * 32 + q * 8 + 4];
            bfr[4 + kc] = pack8(a, c);
        }

        facc acc[8];
#pragma unroll
        for (int mt = 0; mt < 8; ++mt) { facc z = {0.f, 0.f, 0.f, 0.f}; acc[mt] = z; }

#pragma unroll
        for (int mt = 0; mt < 8; ++mt) {
            const unsigned short* wrow = &sW[(mt * 16 + j) * K2];
            const int rs = j & 7;
#pragma unroll
            for (int kc = 0; kc < 8; ++kc) {
                int ch = kc * 4 + q;
                frag8 a = *(const frag8*)&wrow[(ch ^ rs) * 8];
                acc[mt] = __builtin_amdgcn_mfma_f32_16x16x32_bf16(a, bfr[kc], acc[mt], 0, 0, 0);
            }
        }

        if (valid) {
            float* orow = out + (size_t)n * D_OUT;
#pragma unroll
            for (int mt = 0; mt < 8; ++mt)
#pragma unroll
                for (int r = 0; r < 4; ++r)
                    orow[mt * 16 + q * 4 + r] = fmaxf(acc[mt][r] + bias[mt * 4 + r], 0.f);
        }
    }
}

extern "C" void kernel_launch(void* const* d_in, const int* in_sizes, int n_in,
                              void* d_out, int out_size, void* d_ws, size_t ws_size,
                              hipStream_t stream) {
    const float* node_emb = (const float*)d_in[0];
    const int*   edge_idx = (const int*)d_in[1];
    const float* edge_emb = (const float*)d_in[2];
    const float* W_msg    = (const float*)d_in[3];
    const float* b_msg    = (const float*)d_in[4];
    const float* W_upd    = (const float*)d_in[5];
    const float* b_upd    = (const float*)d_in[6];
    float* out = (float*)d_out;

    const int* src = edge_idx;
    const int* dst = edge_idx + N_EDGES;

    char* W = (char*)d_ws;
    float* mean  = (float*)W;                               // 51,200,000 B
    int* cnt     = (int*)(W + 51200000);                    //    400,000 B
    int* cursor  = (int*)(W + 51600000);                    //    400,000 B
    int* base    = (int*)(W + 52000000);                    //    400,000 B
    int* part    = (int*)(W + 52400000);                    //        512 B
    int* perm    = (int*)(W + 52400512);                    //  6,400,000 B
    int* dstS    = (int*)(W + 58800512);                    //  6,400,000 B
    unsigned short* WtM = (unsigned short*)(W + 65200512);  //     49,152 B
    unsigned short* WtU = (unsigned short*)(W + 65249664);  //     65,536 B

    // zero mean + cnt + cursor (contiguous)
    hipMemsetAsync(d_ws, 0, 52000000, stream);

    prep_kernel<<<224, 256, 0, stream>>>(W_msg, W_upd, WtM, WtU);
    hist_kernel<<<1024, 256, 0, stream>>>(dst, cnt);
    scan_blocks<<<NSB, 1024, 0, stream>>>(cnt, base, part);
    scan_partials<<<1, 64, 0, stream>>>(part);
    scan_add<<<NSB, 1024, 0, stream>>>(base, part);
    scatter_kernel<<<1024, 256, 0, stream>>>(dst, base, cursor, perm, dstS);
    msg_agg_kernel<<<6250, 256, 0, stream>>>(node_emb, src, edge_emb, WtM,
                                             b_msg, perm, dstS, cnt, mean);
    node_kernel<<<391, 256, 0, stream>>>(node_emb, mean, WtU, b_upd, out);
}

// Round 4
// 852.634 us; speedup vs baseline: 7.6091x; 1.4756x over previous
//
#include <hip/hip_runtime.h>
#include <hip/hip_bf16.h>

#define N_NODES 100000
#define N_EDGES 1600000
#define D_NODE 128
#define D_EDGE 64
#define D_MSG 128
#define K1 192   // NODE_DIM + EDGE_DIM
#define K2 256   // NODE_DIM + MSG_DIM
#define D_OUT 128
#define NSB 98   // scan blocks: ceil(100000/1024)

using frag8 = __attribute__((ext_vector_type(8))) short;   // 8 bf16 (4 VGPRs)
using facc  = __attribute__((ext_vector_type(4))) float;   // 4 f32 acc

static __device__ __forceinline__ unsigned short f2bf(float f) {
    unsigned int u = __float_as_uint(f);
    u = u + 0x7fffu + ((u >> 16) & 1u);   // RNE
    return (unsigned short)(u >> 16);
}
static __device__ __forceinline__ float bflo(unsigned int u) {
    return __uint_as_float(u << 16);
}
static __device__ __forceinline__ float bfhi(unsigned int u) {
    return __uint_as_float(u & 0xffff0000u);
}

union F8 { unsigned short s[8]; frag8 f; };

static __device__ __forceinline__ frag8 pack8(float4 a, float4 b) {
    F8 u;
    u.s[0] = f2bf(a.x); u.s[1] = f2bf(a.y); u.s[2] = f2bf(a.z); u.s[3] = f2bf(a.w);
    u.s[4] = f2bf(b.x); u.s[5] = f2bf(b.y); u.s[6] = f2bf(b.z); u.s[7] = f2bf(b.w);
    return u.f;
}

// ---------------------------------------------------------------------------
// Prep: W transposed to [out][k] bf16 in ws.
// ---------------------------------------------------------------------------
__global__ void prep_w_kernel(const float* __restrict__ Wm, const float* __restrict__ Wu,
                              unsigned short* __restrict__ WtM, unsigned short* __restrict__ WtU) {
    int idx0 = blockIdx.x * blockDim.x + threadIdx.x;
    int stride = gridDim.x * blockDim.x;
    for (int idx = idx0; idx < 128 * K1; idx += stride) {
        int o = idx / K1, k = idx - o * K1;
        WtM[idx] = f2bf(Wm[k * D_MSG + o]);
    }
    for (int idx = idx0; idx < 128 * K2; idx += stride) {
        int o = idx >> 8, k = idx & 255;
        WtU[idx] = f2bf(Wu[k * D_OUT + o]);
    }
}

// node_emb f32 -> bf16 (packed u32 pairs)
__global__ void prep_node_kernel(const float* __restrict__ node_emb,
                                 unsigned int* __restrict__ nodeB32) {
    int idx0 = blockIdx.x * blockDim.x + threadIdx.x;
    int stride = gridDim.x * blockDim.x;
    const int total = N_NODES * 64;   // u32 pairs
    for (int i = idx0; i < total; i += stride) {
        float2 v = *(const float2*)&node_emb[(size_t)i * 2];
        nodeB32[i] = (unsigned)f2bf(v.x) | ((unsigned)f2bf(v.y) << 16);
    }
}

__global__ void hist_kernel(const int* __restrict__ dst, int* __restrict__ cnt) {
    int idx0 = blockIdx.x * blockDim.x + threadIdx.x;
    int stride = gridDim.x * blockDim.x;
    for (int e = idx0; e < N_EDGES; e += stride) {
        int d = min(max(dst[e], 0), N_NODES - 1);
        atomicAdd(&cnt[d], 1);
    }
}

__global__ __launch_bounds__(1024) void scan_blocks(const int* __restrict__ cnt,
                                                    int* __restrict__ base,
                                                    int* __restrict__ part) {
    __shared__ int sh[1024];
    int i = blockIdx.x * 1024 + threadIdx.x;
    int c = (i < N_NODES) ? cnt[i] : 0;
    sh[threadIdx.x] = c;
    __syncthreads();
    for (int s = 1; s < 1024; s <<= 1) {
        int t = (threadIdx.x >= s) ? sh[threadIdx.x - s] : 0;
        __syncthreads();
        sh[threadIdx.x] += t;
        __syncthreads();
    }
    if (i < N_NODES) base[i] = sh[threadIdx.x] - c;   // exclusive within block
    if (threadIdx.x == 1023) part[blockIdx.x] = sh[1023];
}

__global__ __launch_bounds__(128) void scan_partials(int* __restrict__ part) {
    __shared__ int sh[128];
    int i = threadIdx.x;
    int c = (i < NSB) ? part[i] : 0;
    sh[i] = c;
    __syncthreads();
    for (int s = 1; s < 128; s <<= 1) {
        int t = (i >= s) ? sh[i - s] : 0;
        __syncthreads();
        sh[i] += t;
        __syncthreads();
    }
    if (i < NSB) part[i] = sh[i] - c;   // exclusive
}

__global__ __launch_bounds__(1024) void scan_add(int* __restrict__ base, const int* __restrict__ part) {
    int i = blockIdx.x * 1024 + threadIdx.x;
    if (i < N_NODES) base[i] += part[blockIdx.x];
}

// bins edges by dst; writes perm (orig index) and aux = val[e] in sorted order
__global__ void scatter_kernel(const int* __restrict__ dst, const int* __restrict__ val,
                               const int* __restrict__ base, int* __restrict__ cursor,
                               int* __restrict__ perm, int* __restrict__ aux) {
    int idx0 = blockIdx.x * blockDim.x + threadIdx.x;
    int stride = gridDim.x * blockDim.x;
    for (int e = idx0; e < N_EDGES; e += stride) {
        int d = min(max(dst[e], 0), N_NODES - 1);
        int pos = base[d] + atomicAdd(&cursor[d], 1);
        perm[pos] = e;
        aux[pos] = val[e];
    }
}

// ---------------------------------------------------------------------------
// FAST PATH Phase A: dense msg GEMM over sorted edges -> msgS bf16 [E][128].
// No shuffles/carry/atomics. Lane (j,q): edge col j, outs mt*16+q*4+r.
// ---------------------------------------------------------------------------
__global__ __launch_bounds__(256) void msg_gemm_kernel(
    const unsigned short* __restrict__ nodeB, const int* __restrict__ srcS,
    const int* __restrict__ perm, const float* __restrict__ edge_emb,
    const unsigned short* __restrict__ WtM, const float* __restrict__ b_msg,
    unsigned short* __restrict__ msgS)
{
    __shared__ unsigned short sW[128 * K1];   // 49152 B, chunk-XOR-swizzled

    for (int idx = threadIdx.x; idx < 128 * 24; idx += 256) {
        int o = idx / 24, ch = idx % 24;
        *(uint4*)&sW[o * K1 + (ch ^ (o & 7)) * 8] = *(const uint4*)&WtM[o * K1 + ch * 8];
    }

    const int lane = threadIdx.x & 63;
    const int wav  = threadIdx.x >> 6;
    const int j = lane & 15;
    const int q = lane >> 4;
    const int rs = j & 7;

    float bias[32];
#pragma unroll
    for (int mt = 0; mt < 8; ++mt)
#pragma unroll
        for (int r = 0; r < 4; ++r) bias[mt * 4 + r] = b_msg[mt * 16 + q * 4 + r];
    __syncthreads();

    const int e0w = blockIdx.x * 256 + wav * 64;

#pragma unroll 1
    for (int g = 0; g < 4; ++g) {
        const int e = e0w + g * 16 + j;
        const int p = perm[e];
        const int sp = min(max(srcS[e], 0), N_NODES - 1);

        frag8 bfr[6];
        const unsigned short* nrow = nodeB + (size_t)sp * D_NODE;
#pragma unroll
        for (int kc = 0; kc < 4; ++kc)
            bfr[kc] = *(const frag8*)&nrow[kc * 32 + q * 8];   // bf16 direct
        const float* erow = edge_emb + (size_t)p * D_EDGE;
#pragma unroll
        for (int kc = 0; kc < 2; ++kc) {
            float4 a = *(const float4*)&erow[kc * 32 + q * 8];
            float4 c = *(const float4*)&erow[kc * 32 + q * 8 + 4];
            bfr[4 + kc] = pack8(a, c);
        }

        facc acc[8];
#pragma unroll
        for (int mt = 0; mt < 8; ++mt) { facc z = {0.f, 0.f, 0.f, 0.f}; acc[mt] = z; }

#pragma unroll
        for (int mt = 0; mt < 8; ++mt) {
            const unsigned short* wrow = &sW[(mt * 16 + j) * K1];
#pragma unroll
            for (int kc = 0; kc < 6; ++kc) {
                frag8 a = *(const frag8*)&wrow[((kc * 4 + q) ^ rs) * 8];
                acc[mt] = __builtin_amdgcn_mfma_f32_16x16x32_bf16(a, bfr[kc], acc[mt], 0, 0, 0);
            }
        }

        // bias + relu + cvt bf16; direct 8B stores (wave covers 16 rows x 256B)
        unsigned short* orow = msgS + (size_t)e * D_MSG;
#pragma unroll
        for (int mt = 0; mt < 8; ++mt) {
            float t0 = fmaxf(acc[mt][0] + bias[mt * 4 + 0], 0.f);
            float t1 = fmaxf(acc[mt][1] + bias[mt * 4 + 1], 0.f);
            float t2 = fmaxf(acc[mt][2] + bias[mt * 4 + 2], 0.f);
            float t3 = fmaxf(acc[mt][3] + bias[mt * 4 + 3], 0.f);
            uint2 w;
            w.x = (unsigned)f2bf(t0) | ((unsigned)f2bf(t1) << 16);
            w.y = (unsigned)f2bf(t2) | ((unsigned)f2bf(t3) << 16);
            *(uint2*)&orow[mt * 16 + q * 4] = w;
        }
    }
}

// ---------------------------------------------------------------------------
// FAST PATH Phase B: mean per node. Wave per node, contiguous row reads.
// ---------------------------------------------------------------------------
__global__ __launch_bounds__(256) void mean_kernel(
    const unsigned short* __restrict__ msgS, const int* __restrict__ cnt,
    const int* __restrict__ base, unsigned int* __restrict__ meanB32)
{
    const int wav = threadIdx.x >> 6;
    const int lane = threadIdx.x & 63;
    const int n = blockIdx.x * 4 + wav;
    const int c = cnt[n];
    const int b = base[n];
    const unsigned int* rows = (const unsigned int*)msgS + (size_t)b * 64 + lane;

    float s0a = 0.f, s1a = 0.f, s0b = 0.f, s1b = 0.f;
    int i = 0;
    for (; i + 2 <= c; i += 2) {
        unsigned int u0 = rows[(size_t)(i + 0) * 64];
        unsigned int u1 = rows[(size_t)(i + 1) * 64];
        s0a += bflo(u0); s1a += bfhi(u0);
        s0b += bflo(u1); s1b += bfhi(u1);
    }
    if (i < c) {
        unsigned int u0 = rows[(size_t)i * 64];
        s0a += bflo(u0); s1a += bfhi(u0);
    }
    float inv = 1.0f / fmaxf((float)c, 1.0f);
    float s0 = (s0a + s0b) * inv;
    float s1 = (s1a + s1b) * inv;
    meanB32[(size_t)n * 64 + lane] = (unsigned)f2bf(s0) | ((unsigned)f2bf(s1) << 16);
}

// ---------------------------------------------------------------------------
// FAST PATH Phase C: node GEMM, all-bf16 fragment loads.
// ---------------------------------------------------------------------------
__global__ __launch_bounds__(256) void node_gemm_kernel(
    const unsigned short* __restrict__ nodeB, const unsigned short* __restrict__ meanB,
    const unsigned short* __restrict__ WtU, const float* __restrict__ b_upd,
    float* __restrict__ out)
{
    __shared__ unsigned short sW[128 * K2];   // 65536 B

    for (int idx = threadIdx.x; idx < 128 * 32; idx += 256) {
        int o = idx >> 5, ch = idx & 31;
        *(uint4*)&sW[o * K2 + (ch ^ (o & 7)) * 8] = *(const uint4*)&WtU[o * K2 + ch * 8];
    }

    const int lane = threadIdx.x & 63;
    const int wav  = threadIdx.x >> 6;
    const int j = lane & 15;
    const int q = lane >> 4;
    const int rs = j & 7;

    float bias[32];
#pragma unroll
    for (int mt = 0; mt < 8; ++mt)
#pragma unroll
        for (int r = 0; r < 4; ++r) bias[mt * 4 + r] = b_upd[mt * 16 + q * 4 + r];
    __syncthreads();

    const int n0w = blockIdx.x * 256 + wav * 64;

#pragma unroll 1
    for (int g = 0; g < 4; ++g) {
        const int n = n0w + g * 16 + j;
        const bool valid = (n < N_NODES);
        const size_t nn = valid ? (size_t)n : 0;

        frag8 bfr[8];
        const unsigned short* nrow = nodeB + nn * D_NODE;
#pragma unroll
        for (int kc = 0; kc < 4; ++kc)
            bfr[kc] = *(const frag8*)&nrow[kc * 32 + q * 8];
        const unsigned short* mrow = meanB + nn * D_MSG;
#pragma unroll
        for (int kc = 0; kc < 4; ++kc)
            bfr[4 + kc] = *(const frag8*)&mrow[kc * 32 + q * 8];

        facc acc[8];
#pragma unroll
        for (int mt = 0; mt < 8; ++mt) { facc z = {0.f, 0.f, 0.f, 0.f}; acc[mt] = z; }

#pragma unroll
        for (int mt = 0; mt < 8; ++mt) {
            const unsigned short* wrow = &sW[(mt * 16 + j) * K2];
#pragma unroll
            for (int kc = 0; kc < 8; ++kc) {
                frag8 a = *(const frag8*)&wrow[((kc * 4 + q) ^ rs) * 8];
                acc[mt] = __builtin_amdgcn_mfma_f32_16x16x32_bf16(a, bfr[kc], acc[mt], 0, 0, 0);
            }
        }

        if (valid) {
            float* orow = out + (size_t)n * D_OUT;
#pragma unroll
            for (int mt = 0; mt < 8; ++mt)
#pragma unroll
                for (int r = 0; r < 4; ++r)
                    orow[mt * 16 + q * 4 + r] = fmaxf(acc[mt][r] + bias[mt * 4 + r], 0.f);
        }
    }
}

// ===========================================================================
// FALLBACK PATH (round-3 verbatim): fused msg+aggregate, f32 mean, if ws is
// too small for the msg scratch buffer.
// ===========================================================================
__global__ __launch_bounds__(256) void msg_agg_kernel_fb(
    const float* __restrict__ node_emb, const int* __restrict__ src,
    const float* __restrict__ edge_emb, const unsigned short* __restrict__ WtM,
    const float* __restrict__ b_msg, const int* __restrict__ perm,
    const int* __restrict__ dstS, const int* __restrict__ cnt,
    float* __restrict__ mean)
{
    __shared__ unsigned short sW[128 * K1];

    for (int idx = threadIdx.x; idx < 128 * 24; idx += 256) {
        int o = idx / 24, ch = idx % 24;
        *(uint4*)&sW[o * K1 + (ch ^ (o & 7)) * 8] = *(const uint4*)&WtM[o * K1 + ch * 8];
    }

    const int lane = threadIdx.x & 63;
    const int wav  = threadIdx.x >> 6;
    const int j = lane & 15;
    const int q = lane >> 4;

    float bias[32];
#pragma unroll
    for (int mt = 0; mt < 8; ++mt)
#pragma unroll
        for (int r = 0; r < 4; ++r) bias[mt * 4 + r] = b_msg[mt * 16 + q * 4 + r];
    __syncthreads();

    const int e0w = blockIdx.x * 256 + wav * 64;
    float carry[32];
    int carry_d = -1;

#pragma unroll 1
    for (int g = 0; g < 4; ++g) {
        const int e = e0w + g * 16 + j;
        const int p = perm[e];
        const int d = dstS[e];
        const int sp = min(max(src[p], 0), N_NODES - 1);
        const float invc = 1.0f / (float)cnt[d];

        frag8 bfr[6];
        const float* nrow = node_emb + (size_t)sp * D_NODE;
#pragma unroll
        for (int kc = 0; kc < 4; ++kc) {
            float4 a = *(const float4*)&nrow[kc * 32 + q * 8];
            float4 c = *(const float4*)&nrow[kc * 32 + q * 8 + 4];
            bfr[kc] = pack8(a, c);
        }
        const float* erow = edge_emb + (size_t)p * D_EDGE;
#pragma unroll
        for (int kc = 0; kc < 2; ++kc) {
            float4 a = *(const float4*)&erow[kc * 32 + q * 8];
            float4 c = *(const float4*)&erow[kc * 32 + q * 8 + 4];
            bfr[4 + kc] = pack8(a, c);
        }

        facc acc[8];
#pragma unroll
        for (int mt = 0; mt < 8; ++mt) { facc z = {0.f, 0.f, 0.f, 0.f}; acc[mt] = z; }

#pragma unroll
        for (int mt = 0; mt < 8; ++mt) {
            const unsigned short* wrow = &sW[(mt * 16 + j) * K1];
            const int rs = j & 7;
#pragma unroll
            for (int kc = 0; kc < 6; ++kc) {
                frag8 a = *(const frag8*)&wrow[((kc * 4 + q) ^ rs) * 8];
                acc[mt] = __builtin_amdgcn_mfma_f32_16x16x32_bf16(a, bfr[kc], acc[mt], 0, 0, 0);
            }
        }

        float v[32];
#pragma unroll
        for (int mt = 0; mt < 8; ++mt)
#pragma unroll
            for (int r = 0; r < 4; ++r) {
                float t = acc[mt][r] + bias[mt * 4 + r];
                v[mt * 4 + r] = fmaxf(t, 0.f) * invc;
            }

        int dprev = __shfl_up(d, 1, 16);
        int head = (j == 0 || d != dprev) ? 1 : 0;
        int seg = head;
#pragma unroll
        for (int s = 1; s < 16; s <<= 1) { int t = __shfl_up(seg, s, 16); if (j >= s) seg += t; }
        int sg1 = __shfl_up(seg, 1, 16);
        int sg2 = __shfl_up(seg, 2, 16);
        int sg4 = __shfl_up(seg, 4, 16);
        int sg8 = __shfl_up(seg, 8, 16);
        bool ok1 = (j >= 1) && (sg1 == seg);
        bool ok2 = (j >= 2) && (sg2 == seg);
        bool ok4 = (j >= 4) && (sg4 == seg);
        bool ok8 = (j >= 8) && (sg8 == seg);

#pragma unroll
        for (int i = 0; i < 32; ++i) { float t = __shfl_up(v[i], 1, 16); if (ok1) v[i] += t; }
#pragma unroll
        for (int i = 0; i < 32; ++i) { float t = __shfl_up(v[i], 2, 16); if (ok2) v[i] += t; }
#pragma unroll
        for (int i = 0; i < 32; ++i) { float t = __shfl_up(v[i], 4, 16); if (ok4) v[i] += t; }
#pragma unroll
        for (int i = 0; i < 32; ++i) { float t = __shfl_up(v[i], 8, 16); if (ok8) v[i] += t; }

        int d0 = __shfl(d, 0, 16);
        if (g > 0) {
            if (d0 != carry_d) {
                if (j == 0) {
                    float* mrow = mean + (size_t)carry_d * D_MSG;
#pragma unroll
                    for (int mt = 0; mt < 8; ++mt)
#pragma unroll
                        for (int r = 0; r < 4; ++r)
                            atomicAdd(&mrow[mt * 16 + q * 4 + r], carry[mt * 4 + r]);
                }
            } else if (seg == 1) {
#pragma unroll
                for (int i = 0; i < 32; ++i) v[i] += carry[i];
            }
        }

#pragma unroll
        for (int i = 0; i < 32; ++i) carry[i] = __shfl(v[i], 15, 16);
        carry_d = __shfl(d, 15, 16);

        int dnext = __shfl_down(d, 1, 16);
        bool tail = (j < 15) ? (dnext != d) : (g == 3);
        if (tail) {
            float* mrow = mean + (size_t)d * D_MSG;
#pragma unroll
            for (int mt = 0; mt < 8; ++mt)
#pragma unroll
                for (int r = 0; r < 4; ++r)
                    atomicAdd(&mrow[mt * 16 + q * 4 + r], v[mt * 4 + r]);
        }
    }
}

__global__ __launch_bounds__(256) void node_kernel_fb(
    const float* __restrict__ node_emb, const float* __restrict__ mean,
    const unsigned short* __restrict__ WtU, const float* __restrict__ b_upd,
    float* __restrict__ out)
{
    __shared__ unsigned short sW[128 * K2];

    for (int idx = threadIdx.x; idx < 128 * 32; idx += 256) {
        int o = idx >> 5, ch = idx & 31;
        *(uint4*)&sW[o * K2 + (ch ^ (o & 7)) * 8] = *(const uint4*)&WtU[o * K2 + ch * 8];
    }

    const int lane = threadIdx.x & 63;
    const int wav  = threadIdx.x >> 6;
    const int j = lane & 15;
    const int q = lane >> 4;

    float bias[32];
#pragma unroll
    for (int mt = 0; mt < 8; ++mt)
#pragma unroll
        for (int r = 0; r < 4; ++r) bias[mt * 4 + r] = b_upd[mt * 16 + q * 4 + r];
    __syncthreads();

    const int n0w = blockIdx.x * 256 + wav * 64;

#pragma unroll 1
    for (int g = 0; g < 4; ++g) {
        const int n = n0w + g * 16 + j;
        const bool valid = (n < N_NODES);
        const size_t nn = valid ? (size_t)n : 0;

        frag8 bfr[8];
        const float* nrow = node_emb + nn * D_NODE;
#pragma unroll
        for (int kc = 0; kc < 4; ++kc) {
            float4 a = *(const float4*)&nrow[kc * 32 + q * 8];
            float4 c = *(const float4*)&nrow[kc * 32 + q * 8 + 4];
            bfr[kc] = pack8(a, c);
        }
        const float* mrow = mean + nn * D_MSG;
#pragma unroll
        for (int kc = 0; kc < 4; ++kc) {
            float4 a = *(const float4*)&mrow[kc * 32 + q * 8];
            float4 c = *(const float4*)&mrow[kc * 32 + q * 8 + 4];
            bfr[4 + kc] = pack8(a, c);
        }

        facc acc[8];
#pragma unroll
        for (int mt = 0; mt < 8; ++mt) { facc z = {0.f, 0.f, 0.f, 0.f}; acc[mt] = z; }

#pragma unroll
        for (int mt = 0; mt < 8; ++mt) {
            const unsigned short* wrow = &sW[(mt * 16 + j) * K2];
            const int rs = j & 7;
#pragma unroll
            for (int kc = 0; kc < 8; ++kc) {
                frag8 a = *(const frag8*)&wrow[((kc * 4 + q) ^ rs) * 8];
                acc[mt] = __builtin_amdgcn_mfma_f32_16x16x32_bf16(a, bfr[kc], acc[mt], 0, 0, 0);
            }
        }

        if (valid) {
            float* orow = out + (size_t)n * D_OUT;
#pragma unroll
            for (int mt = 0; mt < 8; ++mt)
#pragma unroll
                for (int r = 0; r < 4; ++r)
                    orow[mt * 16 + q * 4 + r] = fmaxf(acc[mt][r] + bias[mt * 4 + r], 0.f);
        }
    }
}

extern "C" void kernel_launch(void* const* d_in, const int* in_sizes, int n_in,
                              void* d_out, int out_size, void* d_ws, size_t ws_size,
                              hipStream_t stream) {
    const float* node_emb = (const float*)d_in[0];
    const int*   edge_idx = (const int*)d_in[1];
    const float* edge_emb = (const float*)d_in[2];
    const float* W_msg    = (const float*)d_in[3];
    const float* b_msg    = (const float*)d_in[4];
    const float* W_upd    = (const float*)d_in[5];
    const float* b_upd    = (const float*)d_in[6];
    float* out = (float*)d_out;

    const int* src = edge_idx;
    const int* dst = edge_idx + N_EDGES;

    char* W = (char*)d_ws;

    if (ws_size >= 474915200ULL) {
        // ---- FAST PATH ----
        int* cnt     = (int*)(W + 0);                           //    400,000
        int* cursor  = (int*)(W + 400000);                      //    400,000
        int* base    = (int*)(W + 800000);                      //    400,000
        int* part    = (int*)(W + 1200000);                     //        512
        int* perm    = (int*)(W + 1200512);                     //  6,400,000
        int* srcS    = (int*)(W + 7600512);                     //  6,400,000
        unsigned short* WtM   = (unsigned short*)(W + 14000512);  //   49,152
        unsigned short* WtU   = (unsigned short*)(W + 14049664);  //   65,536
        unsigned short* nodeB = (unsigned short*)(W + 14115200);  // 25,600,000
        unsigned short* meanB = (unsigned short*)(W + 39715200);  // 25,600,000
        unsigned short* msgS  = (unsigned short*)(W + 65315200);  // 409,600,000

        hipMemsetAsync(d_ws, 0, 800000, stream);   // cnt + cursor

        prep_w_kernel<<<224, 256, 0, stream>>>(W_msg, W_upd, WtM, WtU);
        prep_node_kernel<<<2048, 256, 0, stream>>>(node_emb, (unsigned int*)nodeB);
        hist_kernel<<<1024, 256, 0, stream>>>(dst, cnt);
        scan_blocks<<<NSB, 1024, 0, stream>>>(cnt, base, part);
        scan_partials<<<1, 128, 0, stream>>>(part);
        scan_add<<<NSB, 1024, 0, stream>>>(base, part);
        scatter_kernel<<<1024, 256, 0, stream>>>(dst, src, base, cursor, perm, srcS);
        msg_gemm_kernel<<<6250, 256, 0, stream>>>(nodeB, srcS, perm, edge_emb,
                                                  WtM, b_msg, msgS);
        mean_kernel<<<25000, 256, 0, stream>>>(msgS, cnt, base, (unsigned int*)meanB);
        node_gemm_kernel<<<391, 256, 0, stream>>>(nodeB, meanB, WtU, b_upd, out);
    } else {
        // ---- FALLBACK (round-3 layout & kernels) ----
        float* mean  = (float*)W;                               // 51,200,000
        int* cnt     = (int*)(W + 51200000);
        int* cursor  = (int*)(W + 51600000);
        int* base    = (int*)(W + 52000000);
        int* part    = (int*)(W + 52400000);
        int* perm    = (int*)(W + 52400512);
        int* dstS    = (int*)(W + 58800512);
        unsigned short* WtM = (unsigned short*)(W + 65200512);
        unsigned short* WtU = (unsigned short*)(W + 65249664);

        hipMemsetAsync(d_ws, 0, 52000000, stream);

        prep_w_kernel<<<224, 256, 0, stream>>>(W_msg, W_upd, WtM, WtU);
        hist_kernel<<<1024, 256, 0, stream>>>(dst, cnt);
        scan_blocks<<<NSB, 1024, 0, stream>>>(cnt, base, part);
        scan_partials<<<1, 128, 0, stream>>>(part);
        scan_add<<<NSB, 1024, 0, stream>>>(base, part);
        scatter_kernel<<<1024, 256, 0, stream>>>(dst, dst, base, cursor, perm, dstS);
        msg_agg_kernel_fb<<<6250, 256, 0, stream>>>(node_emb, src, edge_emb, WtM,
                                                    b_msg, perm, dstS, cnt, mean);
        node_kernel_fb<<<391, 256, 0, stream>>>(node_emb, mean, WtU, b_upd, out);
    }
}

// Round 5
// 720.523 us; speedup vs baseline: 9.0042x; 1.1834x over previous
//
#include <hip/hip_runtime.h>
#include <hip/hip_bf16.h>

#define N_NODES 100000
#define N_EDGES 1600000
#define D_NODE 128
#define D_EDGE 64
#define D_MSG 128
#define K1 192   // NODE_DIM + EDGE_DIM
#define K2 256   // NODE_DIM + MSG_DIM
#define D_OUT 128
#define NSB 98   // scan blocks: ceil(100000/1024)
#define TILE 64
#define NT (N_EDGES / TILE)   // 25000 exact
#define LROW 200              // LDS row stride in bf16 elems (192 + 8 pad -> 2-way only)

using frag8 = __attribute__((ext_vector_type(8))) short;   // 8 bf16 (4 VGPRs)
using facc  = __attribute__((ext_vector_type(4))) float;   // 4 f32 acc

static __device__ __forceinline__ unsigned short f2bf(float f) {
    unsigned int u = __float_as_uint(f);
    u = u + 0x7fffu + ((u >> 16) & 1u);   // RNE
    return (unsigned short)(u >> 16);
}
static __device__ __forceinline__ float bflo(unsigned int u) { return __uint_as_float(u << 16); }
static __device__ __forceinline__ float bfhi(unsigned int u) { return __uint_as_float(u & 0xffff0000u); }

union F8 { unsigned short s[8]; frag8 f; };

static __device__ __forceinline__ frag8 pack8(float4 a, float4 b) {
    F8 u;
    u.s[0] = f2bf(a.x); u.s[1] = f2bf(a.y); u.s[2] = f2bf(a.z); u.s[3] = f2bf(a.w);
    u.s[4] = f2bf(b.x); u.s[5] = f2bf(b.y); u.s[6] = f2bf(b.z); u.s[7] = f2bf(b.w);
    return u.f;
}

// ---------------------------------------------------------------------------
// Prep: W transposed to [out][k] bf16 in ws.
// ---------------------------------------------------------------------------
__global__ void prep_w_kernel(const float* __restrict__ Wm, const float* __restrict__ Wu,
                              unsigned short* __restrict__ WtM, unsigned short* __restrict__ WtU) {
    int idx0 = blockIdx.x * blockDim.x + threadIdx.x;
    int stride = gridDim.x * blockDim.x;
    for (int idx = idx0; idx < 128 * K1; idx += stride) {
        int o = idx / K1, k = idx - o * K1;
        WtM[idx] = f2bf(Wm[k * D_MSG + o]);
    }
    for (int idx = idx0; idx < 128 * K2; idx += stride) {
        int o = idx >> 8, k = idx & 255;
        WtU[idx] = f2bf(Wu[k * D_OUT + o]);
    }
}

// node_emb f32 -> bf16 (packed u32 pairs)
__global__ void prep_node_kernel(const float* __restrict__ node_emb,
                                 unsigned int* __restrict__ nodeB32) {
    int idx0 = blockIdx.x * blockDim.x + threadIdx.x;
    int stride = gridDim.x * blockDim.x;
    const int total = N_NODES * 64;   // u32 pairs
    for (int i = idx0; i < total; i += stride) {
        float2 v = *(const float2*)&node_emb[(size_t)i * 2];
        nodeB32[i] = (unsigned)f2bf(v.x) | ((unsigned)f2bf(v.y) << 16);
    }
}

__global__ void hist_kernel(const int* __restrict__ dst, int* __restrict__ cnt) {
    int idx0 = blockIdx.x * blockDim.x + threadIdx.x;
    int stride = gridDim.x * blockDim.x;
    for (int e = idx0; e < N_EDGES; e += stride) {
        int d = min(max(dst[e], 0), N_NODES - 1);
        atomicAdd(&cnt[d], 1);
    }
}

__global__ __launch_bounds__(1024) void scan_blocks(const int* __restrict__ cnt,
                                                    int* __restrict__ base,
                                                    int* __restrict__ part) {
    __shared__ int sh[1024];
    int i = blockIdx.x * 1024 + threadIdx.x;
    int c = (i < N_NODES) ? cnt[i] : 0;
    sh[threadIdx.x] = c;
    __syncthreads();
    for (int s = 1; s < 1024; s <<= 1) {
        int t = (threadIdx.x >= s) ? sh[threadIdx.x - s] : 0;
        __syncthreads();
        sh[threadIdx.x] += t;
        __syncthreads();
    }
    if (i < N_NODES) base[i] = sh[threadIdx.x] - c;   // exclusive within block
    if (threadIdx.x == 1023) part[blockIdx.x] = sh[1023];
}

__global__ __launch_bounds__(128) void scan_partials(int* __restrict__ part) {
    __shared__ int sh[128];
    int i = threadIdx.x;
    int c = (i < NSB) ? part[i] : 0;
    sh[i] = c;
    __syncthreads();
    for (int s = 1; s < 128; s <<= 1) {
        int t = (i >= s) ? sh[i - s] : 0;
        __syncthreads();
        sh[i] += t;
        __syncthreads();
    }
    if (i < NSB) part[i] = sh[i] - c;   // exclusive
}

__global__ __launch_bounds__(1024) void scan_add(int* __restrict__ base, const int* __restrict__ part) {
    int i = blockIdx.x * 1024 + threadIdx.x;
    if (i < N_NODES) base[i] += part[blockIdx.x];
}

// bins edges by dst; writes perm (orig index) and aux = val[e] in sorted order
__global__ void scatter_kernel(const int* __restrict__ dst, const int* __restrict__ val,
                               const int* __restrict__ base, int* __restrict__ cursor,
                               int* __restrict__ perm, int* __restrict__ aux) {
    int idx0 = blockIdx.x * blockDim.x + threadIdx.x;
    int stride = gridDim.x * blockDim.x;
    for (int e = idx0; e < N_EDGES; e += stride) {
        int d = min(max(dst[e], 0), N_NODES - 1);
        int pos = base[d] + atomicAdd(&cursor[d], 1);
        perm[pos] = e;
        aux[pos] = val[e];
    }
}

// ---------------------------------------------------------------------------
// Phase A (v2): pipelined GEMM. W slice per wave in REGISTERS (12 frag8),
// gathered inputs staged bf16 in double-buffered LDS [64][200].
// Wave w computes out rows 32w..32w+31 for all 64 edges of the tile.
// One barrier per tile; stage-loads issued before compute (latency hidden).
// ---------------------------------------------------------------------------
__global__ __launch_bounds__(256) void msg_gemm2_kernel(
    const unsigned short* __restrict__ nodeB, const int* __restrict__ srcS,
    const int* __restrict__ perm, const float* __restrict__ edge_emb,
    const unsigned short* __restrict__ WtM, const float* __restrict__ b_msg,
    unsigned short* __restrict__ msgS)
{
    __shared__ unsigned short sIn[2][TILE][LROW];   // 2 x 25600 B

    const int lane = threadIdx.x & 63;
    const int wav  = threadIdx.x >> 6;
    const int j = lane & 15;
    const int q = lane >> 4;

    // A-fragments (W slice) in registers: mt = 2*wav + m2
    frag8 wfr[2][6];
#pragma unroll
    for (int m2 = 0; m2 < 2; ++m2) {
        const unsigned short* wrow = WtM + ((wav * 2 + m2) * 16 + j) * K1;
#pragma unroll
        for (int kc = 0; kc < 6; ++kc)
            wfr[m2][kc] = *(const frag8*)&wrow[(kc * 4 + q) * 8];
    }
    float bias[2][4];
#pragma unroll
    for (int m2 = 0; m2 < 2; ++m2)
#pragma unroll
        for (int r = 0; r < 4; ++r) bias[m2][r] = b_msg[(wav * 2 + m2) * 16 + q * 4 + r];

    // staging role: thread t covers edge eL = t>>2, quarter qt = t&3
    const int eL = threadIdx.x >> 2;
    const int qt = threadIdx.x & 3;

    uint4  nst[4];    // node part: 4 x 16B bf16
    float4 est[4];    // edge part: 16 f32

    const int t0 = blockIdx.x;
    // ---- prologue: stage tile t0 into buf 0 ----
    {
        const int e = t0 * TILE + eL;
        const int sp = min(max(srcS[e], 0), N_NODES - 1);
        const unsigned short* nrow = nodeB + (size_t)sp * D_NODE + qt * 32;
#pragma unroll
        for (int i = 0; i < 4; ++i) nst[i] = *(const uint4*)&nrow[i * 8];
        const float* erow = edge_emb + (size_t)perm[e] * D_EDGE + qt * 16;
#pragma unroll
        for (int i = 0; i < 4; ++i) est[i] = *(const float4*)&erow[i * 4];

        unsigned short* dstrow = &sIn[0][eL][0];
#pragma unroll
        for (int i = 0; i < 4; ++i) *(uint4*)&dstrow[qt * 32 + i * 8] = nst[i];
#pragma unroll
        for (int h = 0; h < 2; ++h) {
            F8 u;
            u.f = pack8(est[h * 2], est[h * 2 + 1]);
            *(uint4*)&dstrow[128 + qt * 16 + h * 8] = *(uint4*)&u;
        }
    }
    __syncthreads();

    int cur = 0;
#pragma unroll 1
    for (int t = t0; t < NT; t += gridDim.x) {
        const int tn = t + gridDim.x;
        const bool more = (tn < NT);

        // ---- issue next tile's global loads early ----
        if (more) {
            const int e = tn * TILE + eL;
            const int sp = min(max(srcS[e], 0), N_NODES - 1);
            const unsigned short* nrow = nodeB + (size_t)sp * D_NODE + qt * 32;
#pragma unroll
            for (int i = 0; i < 4; ++i) nst[i] = *(const uint4*)&nrow[i * 8];
            const float* erow = edge_emb + (size_t)perm[e] * D_EDGE + qt * 16;
#pragma unroll
            for (int i = 0; i < 4; ++i) est[i] = *(const float4*)&erow[i * 4];
        }

        // ---- compute current tile from LDS ----
        facc acc[2][4];
#pragma unroll
        for (int m2 = 0; m2 < 2; ++m2)
#pragma unroll
            for (int eg = 0; eg < 4; ++eg) { facc z = {0.f,0.f,0.f,0.f}; acc[m2][eg] = z; }

#pragma unroll
        for (int eg = 0; eg < 4; ++eg) {
            const unsigned short* irow = &sIn[cur][eg * 16 + j][0];
#pragma unroll
            for (int kc = 0; kc < 6; ++kc) {
                frag8 b = *(const frag8*)&irow[kc * 32 + q * 8];
                acc[0][eg] = __builtin_amdgcn_mfma_f32_16x16x32_bf16(wfr[0][kc], b, acc[0][eg], 0, 0, 0);
                acc[1][eg] = __builtin_amdgcn_mfma_f32_16x16x32_bf16(wfr[1][kc], b, acc[1][eg], 0, 0, 0);
            }
        }

        // ---- epilogue: bias+relu+cvt, store ----
#pragma unroll
        for (int eg = 0; eg < 4; ++eg) {
            unsigned short* orow = msgS + (size_t)(t * TILE + eg * 16 + j) * D_MSG;
#pragma unroll
            for (int m2 = 0; m2 < 2; ++m2) {
                float v0 = fmaxf(acc[m2][eg][0] + bias[m2][0], 0.f);
                float v1 = fmaxf(acc[m2][eg][1] + bias[m2][1], 0.f);
                float v2 = fmaxf(acc[m2][eg][2] + bias[m2][2], 0.f);
                float v3 = fmaxf(acc[m2][eg][3] + bias[m2][3], 0.f);
                uint2 w;
                w.x = (unsigned)f2bf(v0) | ((unsigned)f2bf(v1) << 16);
                w.y = (unsigned)f2bf(v2) | ((unsigned)f2bf(v3) << 16);
                *(uint2*)&orow[(wav * 2 + m2) * 16 + q * 4] = w;
            }
        }

        // ---- write next tile into the other buffer ----
        if (more) {
            unsigned short* dstrow = &sIn[cur ^ 1][eL][0];
#pragma unroll
            for (int i = 0; i < 4; ++i) *(uint4*)&dstrow[qt * 32 + i * 8] = nst[i];
#pragma unroll
            for (int h = 0; h < 2; ++h) {
                F8 u;
                u.f = pack8(est[h * 2], est[h * 2 + 1]);
                *(uint4*)&dstrow[128 + qt * 16 + h * 8] = *(uint4*)&u;
            }
        }
        __syncthreads();
        cur ^= 1;
    }
}

// ---------------------------------------------------------------------------
// Phase B: mean per node. Wave per node, contiguous row reads.
// ---------------------------------------------------------------------------
__global__ __launch_bounds__(256) void mean_kernel(
    const unsigned short* __restrict__ msgS, const int* __restrict__ cnt,
    const int* __restrict__ base, unsigned int* __restrict__ meanB32)
{
    const int wav = threadIdx.x >> 6;
    const int lane = threadIdx.x & 63;
    const int n = blockIdx.x * 4 + wav;
    const int c = cnt[n];
    const int b = base[n];
    const unsigned int* rows = (const unsigned int*)msgS + (size_t)b * 64 + lane;

    float s0a = 0.f, s1a = 0.f, s0b = 0.f, s1b = 0.f;
    int i = 0;
    for (; i + 2 <= c; i += 2) {
        unsigned int u0 = rows[(size_t)(i + 0) * 64];
        unsigned int u1 = rows[(size_t)(i + 1) * 64];
        s0a += bflo(u0); s1a += bfhi(u0);
        s0b += bflo(u1); s1b += bfhi(u1);
    }
    if (i < c) {
        unsigned int u0 = rows[(size_t)i * 64];
        s0a += bflo(u0); s1a += bfhi(u0);
    }
    float inv = 1.0f / fmaxf((float)c, 1.0f);
    float s0 = (s0a + s0b) * inv;
    float s1 = (s1a + s1b) * inv;
    meanB32[(size_t)n * 64 + lane] = (unsigned)f2bf(s0) | ((unsigned)f2bf(s1) << 16);
}

// ---------------------------------------------------------------------------
// Phase C: node GEMM, all-bf16 fragment loads.
// ---------------------------------------------------------------------------
__global__ __launch_bounds__(256) void node_gemm_kernel(
    const unsigned short* __restrict__ nodeB, const unsigned short* __restrict__ meanB,
    const unsigned short* __restrict__ WtU, const float* __restrict__ b_upd,
    float* __restrict__ out)
{
    __shared__ unsigned short sW[128 * K2];   // 65536 B

    for (int idx = threadIdx.x; idx < 128 * 32; idx += 256) {
        int o = idx >> 5, ch = idx & 31;
        *(uint4*)&sW[o * K2 + (ch ^ (o & 7)) * 8] = *(const uint4*)&WtU[o * K2 + ch * 8];
    }

    const int lane = threadIdx.x & 63;
    const int wav  = threadIdx.x >> 6;
    const int j = lane & 15;
    const int q = lane >> 4;
    const int rs = j & 7;

    float bias[32];
#pragma unroll
    for (int mt = 0; mt < 8; ++mt)
#pragma unroll
        for (int r = 0; r < 4; ++r) bias[mt * 4 + r] = b_upd[mt * 16 + q * 4 + r];
    __syncthreads();

    const int n0w = blockIdx.x * 256 + wav * 64;

#pragma unroll 1
    for (int g = 0; g < 4; ++g) {
        const int n = n0w + g * 16 + j;
        const bool valid = (n < N_NODES);
        const size_t nn = valid ? (size_t)n : 0;

        frag8 bfr[8];
        const unsigned short* nrow = nodeB + nn * D_NODE;
#pragma unroll
        for (int kc = 0; kc < 4; ++kc)
            bfr[kc] = *(const frag8*)&nrow[kc * 32 + q * 8];
        const unsigned short* mrow = meanB + nn * D_MSG;
#pragma unroll
        for (int kc = 0; kc < 4; ++kc)
            bfr[4 + kc] = *(const frag8*)&mrow[kc * 32 + q * 8];

        facc acc[8];
#pragma unroll
        for (int mt = 0; mt < 8; ++mt) { facc z = {0.f, 0.f, 0.f, 0.f}; acc[mt] = z; }

#pragma unroll
        for (int mt = 0; mt < 8; ++mt) {
            const unsigned short* wrow = &sW[(mt * 16 + j) * K2];
#pragma unroll
            for (int kc = 0; kc < 8; ++kc) {
                frag8 a = *(const frag8*)&wrow[((kc * 4 + q) ^ rs) * 8];
                acc[mt] = __builtin_amdgcn_mfma_f32_16x16x32_bf16(a, bfr[kc], acc[mt], 0, 0, 0);
            }
        }

        if (valid) {
            float* orow = out + (size_t)n * D_OUT;
#pragma unroll
            for (int mt = 0; mt < 8; ++mt)
#pragma unroll
                for (int r = 0; r < 4; ++r)
                    orow[mt * 16 + q * 4 + r] = fmaxf(acc[mt][r] + bias[mt * 4 + r], 0.f);
        }
    }
}

// ===========================================================================
// FALLBACK PATH (round-3): fused msg+aggregate if ws too small.
// ===========================================================================
__global__ __launch_bounds__(256) void msg_agg_kernel_fb(
    const float* __restrict__ node_emb, const int* __restrict__ src,
    const float* __restrict__ edge_emb, const unsigned short* __restrict__ WtM,
    const float* __restrict__ b_msg, const int* __restrict__ perm,
    const int* __restrict__ dstS, const int* __restrict__ cnt,
    float* __restrict__ mean)
{
    __shared__ unsigned short sW[128 * K1];

    for (int idx = threadIdx.x; idx < 128 * 24; idx += 256) {
        int o = idx / 24, ch = idx % 24;
        *(uint4*)&sW[o * K1 + (ch ^ (o & 7)) * 8] = *(const uint4*)&WtM[o * K1 + ch * 8];
    }

    const int lane = threadIdx.x & 63;
    const int wav  = threadIdx.x >> 6;
    const int j = lane & 15;
    const int q = lane >> 4;

    float bias[32];
#pragma unroll
    for (int mt = 0; mt < 8; ++mt)
#pragma unroll
        for (int r = 0; r < 4; ++r) bias[mt * 4 + r] = b_msg[mt * 16 + q * 4 + r];
    __syncthreads();

    const int e0w = blockIdx.x * 256 + wav * 64;
    float carry[32];
    int carry_d = -1;

#pragma unroll 1
    for (int g = 0; g < 4; ++g) {
        const int e = e0w + g * 16 + j;
        const int p = perm[e];
        const int d = dstS[e];
        const int sp = min(max(src[p], 0), N_NODES - 1);
        const float invc = 1.0f / (float)cnt[d];

        frag8 bfr[6];
        const float* nrow = node_emb + (size_t)sp * D_NODE;
#pragma unroll
        for (int kc = 0; kc < 4; ++kc) {
            float4 a = *(const float4*)&nrow[kc * 32 + q * 8];
            float4 c = *(const float4*)&nrow[kc * 32 + q * 8 + 4];
            bfr[kc] = pack8(a, c);
        }
        const float* erow = edge_emb + (size_t)p * D_EDGE;
#pragma unroll
        for (int kc = 0; kc < 2; ++kc) {
            float4 a = *(const float4*)&erow[kc * 32 + q * 8];
            float4 c = *(const float4*)&erow[kc * 32 + q * 8 + 4];
            bfr[4 + kc] = pack8(a, c);
        }

        facc acc[8];
#pragma unroll
        for (int mt = 0; mt < 8; ++mt) { facc z = {0.f, 0.f, 0.f, 0.f}; acc[mt] = z; }

#pragma unroll
        for (int mt = 0; mt < 8; ++mt) {
            const unsigned short* wrow = &sW[(mt * 16 + j) * K1];
            const int rs = j & 7;
#pragma unroll
            for (int kc = 0; kc < 6; ++kc) {
                frag8 a = *(const frag8*)&wrow[((kc * 4 + q) ^ rs) * 8];
                acc[mt] = __builtin_amdgcn_mfma_f32_16x16x32_bf16(a, bfr[kc], acc[mt], 0, 0, 0);
            }
        }

        float v[32];
#pragma unroll
        for (int mt = 0; mt < 8; ++mt)
#pragma unroll
            for (int r = 0; r < 4; ++r) {
                float t = acc[mt][r] + bias[mt * 4 + r];
                v[mt * 4 + r] = fmaxf(t, 0.f) * invc;
            }

        int dprev = __shfl_up(d, 1, 16);
        int head = (j == 0 || d != dprev) ? 1 : 0;
        int seg = head;
#pragma unroll
        for (int s = 1; s < 16; s <<= 1) { int t = __shfl_up(seg, s, 16); if (j >= s) seg += t; }
        int sg1 = __shfl_up(seg, 1, 16);
        int sg2 = __shfl_up(seg, 2, 16);
        int sg4 = __shfl_up(seg, 4, 16);
        int sg8 = __shfl_up(seg, 8, 16);
        bool ok1 = (j >= 1) && (sg1 == seg);
        bool ok2 = (j >= 2) && (sg2 == seg);
        bool ok4 = (j >= 4) && (sg4 == seg);
        bool ok8 = (j >= 8) && (sg8 == seg);

#pragma unroll
        for (int i = 0; i < 32; ++i) { float t = __shfl_up(v[i], 1, 16); if (ok1) v[i] += t; }
#pragma unroll
        for (int i = 0; i < 32; ++i) { float t = __shfl_up(v[i], 2, 16); if (ok2) v[i] += t; }
#pragma unroll
        for (int i = 0; i < 32; ++i) { float t = __shfl_up(v[i], 4, 16); if (ok4) v[i] += t; }
#pragma unroll
        for (int i = 0; i < 32; ++i) { float t = __shfl_up(v[i], 8, 16); if (ok8) v[i] += t; }

        int d0 = __shfl(d, 0, 16);
        if (g > 0) {
            if (d0 != carry_d) {
                if (j == 0) {
                    float* mrow = mean + (size_t)carry_d * D_MSG;
#pragma unroll
                    for (int mt = 0; mt < 8; ++mt)
#pragma unroll
                        for (int r = 0; r < 4; ++r)
                            atomicAdd(&mrow[mt * 16 + q * 4 + r], carry[mt * 4 + r]);
                }
            } else if (seg == 1) {
#pragma unroll
                for (int i = 0; i < 32; ++i) v[i] += carry[i];
            }
        }

#pragma unroll
        for (int i = 0; i < 32; ++i) carry[i] = __shfl(v[i], 15, 16);
        carry_d = __shfl(d, 15, 16);

        int dnext = __shfl_down(d, 1, 16);
        bool tail = (j < 15) ? (dnext != d) : (g == 3);
        if (tail) {
            float* mrow = mean + (size_t)d * D_MSG;
#pragma unroll
            for (int mt = 0; mt < 8; ++mt)
#pragma unroll
                for (int r = 0; r < 4; ++r)
                    atomicAdd(&mrow[mt * 16 + q * 4 + r], v[mt * 4 + r]);
        }
    }
}

__global__ __launch_bounds__(256) void node_kernel_fb(
    const float* __restrict__ node_emb, const float* __restrict__ mean,
    const unsigned short* __restrict__ WtU, const float* __restrict__ b_upd,
    float* __restrict__ out)
{
    __shared__ unsigned short sW[128 * K2];

    for (int idx = threadIdx.x; idx < 128 * 32; idx += 256) {
        int o = idx >> 5, ch = idx & 31;
        *(uint4*)&sW[o * K2 + (ch ^ (o & 7)) * 8] = *(const uint4*)&WtU[o * K2 + ch * 8];
    }

    const int lane = threadIdx.x & 63;
    const int wav  = threadIdx.x >> 6;
    const int j = lane & 15;
    const int q = lane >> 4;

    float bias[32];
#pragma unroll
    for (int mt = 0; mt < 8; ++mt)
#pragma unroll
        for (int r = 0; r < 4; ++r) bias[mt * 4 + r] = b_upd[mt * 16 + q * 4 + r];
    __syncthreads();

    const int n0w = blockIdx.x * 256 + wav * 64;

#pragma unroll 1
    for (int g = 0; g < 4; ++g) {
        const int n = n0w + g * 16 + j;
        const bool valid = (n < N_NODES);
        const size_t nn = valid ? (size_t)n : 0;

        frag8 bfr[8];
        const float* nrow = node_emb + nn * D_NODE;
#pragma unroll
        for (int kc = 0; kc < 4; ++kc) {
            float4 a = *(const float4*)&nrow[kc * 32 + q * 8];
            float4 c = *(const float4*)&nrow[kc * 32 + q * 8 + 4];
            bfr[kc] = pack8(a, c);
        }
        const float* mrow = mean + nn * D_MSG;
#pragma unroll
        for (int kc = 0; kc < 4; ++kc) {
            float4 a = *(const float4*)&mrow[kc * 32 + q * 8];
            float4 c = *(const float4*)&mrow[kc * 32 + q * 8 + 4];
            bfr[4 + kc] = pack8(a, c);
        }

        facc acc[8];
#pragma unroll
        for (int mt = 0; mt < 8; ++mt) { facc z = {0.f, 0.f, 0.f, 0.f}; acc[mt] = z; }

#pragma unroll
        for (int mt = 0; mt < 8; ++mt) {
            const unsigned short* wrow = &sW[(mt * 16 + j) * K2];
            const int rs = j & 7;
#pragma unroll
            for (int kc = 0; kc < 8; ++kc) {
                frag8 a = *(const frag8*)&wrow[((kc * 4 + q) ^ rs) * 8];
                acc[mt] = __builtin_amdgcn_mfma_f32_16x16x32_bf16(a, bfr[kc], acc[mt], 0, 0, 0);
            }
        }

        if (valid) {
            float* orow = out + (size_t)n * D_OUT;
#pragma unroll
            for (int mt = 0; mt < 8; ++mt)
#pragma unroll
                for (int r = 0; r < 4; ++r)
                    orow[mt * 16 + q * 4 + r] = fmaxf(acc[mt][r] + bias[mt * 4 + r], 0.f);
        }
    }
}

extern "C" void kernel_launch(void* const* d_in, const int* in_sizes, int n_in,
                              void* d_out, int out_size, void* d_ws, size_t ws_size,
                              hipStream_t stream) {
    const float* node_emb = (const float*)d_in[0];
    const int*   edge_idx = (const int*)d_in[1];
    const float* edge_emb = (const float*)d_in[2];
    const float* W_msg    = (const float*)d_in[3];
    const float* b_msg    = (const float*)d_in[4];
    const float* W_upd    = (const float*)d_in[5];
    const float* b_upd    = (const float*)d_in[6];
    float* out = (float*)d_out;

    const int* src = edge_idx;
    const int* dst = edge_idx + N_EDGES;

    char* W = (char*)d_ws;

    if (ws_size >= 474915200ULL) {
        // ---- FAST PATH ----
        int* cnt     = (int*)(W + 0);                           //    400,000
        int* cursor  = (int*)(W + 400000);                      //    400,000
        int* base    = (int*)(W + 800000);                      //    400,000
        int* part    = (int*)(W + 1200000);                     //        512
        int* perm    = (int*)(W + 1200512);                     //  6,400,000
        int* srcS    = (int*)(W + 7600512);                     //  6,400,000
        unsigned short* WtM   = (unsigned short*)(W + 14000512);  //   49,152
        unsigned short* WtU   = (unsigned short*)(W + 14049664);  //   65,536
        unsigned short* nodeB = (unsigned short*)(W + 14115200);  // 25,600,000
        unsigned short* meanB = (unsigned short*)(W + 39715200);  // 25,600,000
        unsigned short* msgS  = (unsigned short*)(W + 65315200);  // 409,600,000

        hipMemsetAsync(d_ws, 0, 800000, stream);   // cnt + cursor

        prep_w_kernel<<<224, 256, 0, stream>>>(W_msg, W_upd, WtM, WtU);
        prep_node_kernel<<<2048, 256, 0, stream>>>(node_emb, (unsigned int*)nodeB);
        hist_kernel<<<1024, 256, 0, stream>>>(dst, cnt);
        scan_blocks<<<NSB, 1024, 0, stream>>>(cnt, base, part);
        scan_partials<<<1, 128, 0, stream>>>(part);
        scan_add<<<NSB, 1024, 0, stream>>>(base, part);
        scatter_kernel<<<1024, 256, 0, stream>>>(dst, src, base, cursor, perm, srcS);
        msg_gemm2_kernel<<<2048, 256, 0, stream>>>(nodeB, srcS, perm, edge_emb,
                                                   WtM, b_msg, msgS);
        mean_kernel<<<25000, 256, 0, stream>>>(msgS, cnt, base, (unsigned int*)meanB);
        node_gemm_kernel<<<391, 256, 0, stream>>>(nodeB, meanB, WtU, b_upd, out);
    } else {
        // ---- FALLBACK (round-3 layout & kernels) ----
        float* mean  = (float*)W;                               // 51,200,000
        int* cnt     = (int*)(W + 51200000);
        int* cursor  = (int*)(W + 51600000);
        int* base    = (int*)(W + 52000000);
        int* part    = (int*)(W + 52400000);
        int* perm    = (int*)(W + 52400512);
        int* dstS    = (int*)(W + 58800512);
        unsigned short* WtM = (unsigned short*)(W + 65200512);
        unsigned short* WtU = (unsigned short*)(W + 65249664);

        hipMemsetAsync(d_ws, 0, 52000000, stream);

        prep_w_kernel<<<224, 256, 0, stream>>>(W_msg, W_upd, WtM, WtU);
        hist_kernel<<<1024, 256, 0, stream>>>(dst, cnt);
        scan_blocks<<<NSB, 1024, 0, stream>>>(cnt, base, part);
        scan_partials<<<1, 128, 0, stream>>>(part);
        scan_add<<<NSB, 1024, 0, stream>>>(base, part);
        scatter_kernel<<<1024, 256, 0, stream>>>(dst, dst, base, cursor, perm, dstS);
        msg_agg_kernel_fb<<<6250, 256, 0, stream>>>(node_emb, src, edge_emb, WtM,
                                                    b_msg, perm, dstS, cnt, mean);
        node_kernel_fb<<<391, 256, 0, stream>>>(node_emb, mean, WtU, b_upd, out);
    }
}

// Round 6
// 604.909 us; speedup vs baseline: 10.7252x; 1.1911x over previous
//
#include <hip/hip_runtime.h>
#include <hip/hip_bf16.h>

#define N_NODES 100000
#define N_EDGES 1600000
#define D_NODE 128
#define D_EDGE 64
#define D_MSG 128
#define K1 192   // NODE_DIM + EDGE_DIM
#define K2 256   // NODE_DIM + MSG_DIM
#define D_OUT 128
#define NSB 98   // scan blocks: ceil(100000/1024)
#define TILE 64
#define NT (N_EDGES / TILE)   // 25000 exact

using frag8 = __attribute__((ext_vector_type(8))) short;   // 8 bf16 (4 VGPRs)
using facc  = __attribute__((ext_vector_type(4))) float;   // 4 f32 acc

static __device__ __forceinline__ unsigned short f2bf(float f) {
    unsigned int u = __float_as_uint(f);
    u = u + 0x7fffu + ((u >> 16) & 1u);   // RNE
    return (unsigned short)(u >> 16);
}
static __device__ __forceinline__ float bflo(unsigned int u) { return __uint_as_float(u << 16); }
static __device__ __forceinline__ float bfhi(unsigned int u) { return __uint_as_float(u & 0xffff0000u); }

union F8 { unsigned short s[8]; frag8 f; uint4 u4; };

static __device__ __forceinline__ frag8 pack8(float4 a, float4 b) {
    F8 u;
    u.s[0] = f2bf(a.x); u.s[1] = f2bf(a.y); u.s[2] = f2bf(a.z); u.s[3] = f2bf(a.w);
    u.s[4] = f2bf(b.x); u.s[5] = f2bf(b.y); u.s[6] = f2bf(b.z); u.s[7] = f2bf(b.w);
    return u.f;
}

// ---------------------------------------------------------------------------
// Prep kernels
// ---------------------------------------------------------------------------
__global__ void prep_w_kernel(const float* __restrict__ Wm, const float* __restrict__ Wu,
                              unsigned short* __restrict__ WtM, unsigned short* __restrict__ WtU) {
    int idx0 = blockIdx.x * blockDim.x + threadIdx.x;
    int stride = gridDim.x * blockDim.x;
    for (int idx = idx0; idx < 128 * K1; idx += stride) {
        int o = idx / K1, k = idx - o * K1;
        WtM[idx] = f2bf(Wm[k * D_MSG + o]);
    }
    for (int idx = idx0; idx < 128 * K2; idx += stride) {
        int o = idx >> 8, k = idx & 255;
        WtU[idx] = f2bf(Wu[k * D_OUT + o]);
    }
}

__global__ void prep_node_kernel(const float* __restrict__ node_emb,
                                 unsigned int* __restrict__ nodeB32) {
    int idx0 = blockIdx.x * blockDim.x + threadIdx.x;
    int stride = gridDim.x * blockDim.x;
    const int total = N_NODES * 64;   // u32 pairs
    for (int i = idx0; i < total; i += stride) {
        float2 v = *(const float2*)&node_emb[(size_t)i * 2];
        nodeB32[i] = (unsigned)f2bf(v.x) | ((unsigned)f2bf(v.y) << 16);
    }
}

__global__ void hist_kernel(const int* __restrict__ dst, int* __restrict__ cnt) {
    int idx0 = blockIdx.x * blockDim.x + threadIdx.x;
    int stride = gridDim.x * blockDim.x;
    for (int e = idx0; e < N_EDGES; e += stride) {
        int d = min(max(dst[e], 0), N_NODES - 1);
        atomicAdd(&cnt[d], 1);
    }
}

__global__ __launch_bounds__(1024) void scan_blocks(const int* __restrict__ cnt,
                                                    int* __restrict__ base,
                                                    int* __restrict__ part) {
    __shared__ int sh[1024];
    int i = blockIdx.x * 1024 + threadIdx.x;
    int c = (i < N_NODES) ? cnt[i] : 0;
    sh[threadIdx.x] = c;
    __syncthreads();
    for (int s = 1; s < 1024; s <<= 1) {
        int t = (threadIdx.x >= s) ? sh[threadIdx.x - s] : 0;
        __syncthreads();
        sh[threadIdx.x] += t;
        __syncthreads();
    }
    if (i < N_NODES) base[i] = sh[threadIdx.x] - c;   // exclusive within block
    if (threadIdx.x == 1023) part[blockIdx.x] = sh[1023];
}

__global__ __launch_bounds__(128) void scan_partials(int* __restrict__ part) {
    __shared__ int sh[128];
    int i = threadIdx.x;
    int c = (i < NSB) ? part[i] : 0;
    sh[i] = c;
    __syncthreads();
    for (int s = 1; s < 128; s <<= 1) {
        int t = (i >= s) ? sh[i - s] : 0;
        __syncthreads();
        sh[i] += t;
        __syncthreads();
    }
    if (i < NSB) part[i] = sh[i] - c;   // exclusive
}

__global__ __launch_bounds__(1024) void scan_add(int* __restrict__ base, const int* __restrict__ part) {
    int i = blockIdx.x * 1024 + threadIdx.x;
    if (i < N_NODES) base[i] += part[blockIdx.x];
}

// bins edges by dst; emits perm (orig idx), srcS (src in sorted order), dstS
__global__ void scatter_kernel(const int* __restrict__ dst, const int* __restrict__ src,
                               const int* __restrict__ base, int* __restrict__ cursor,
                               int* __restrict__ perm, int* __restrict__ srcS,
                               int* __restrict__ dstS) {
    int idx0 = blockIdx.x * blockDim.x + threadIdx.x;
    int stride = gridDim.x * blockDim.x;
    for (int e = idx0; e < N_EDGES; e += stride) {
        int d = min(max(dst[e], 0), N_NODES - 1);
        int pos = base[d] + atomicAdd(&cursor[d], 1);
        perm[pos] = e;
        srcS[pos] = src[e];
        dstS[pos] = d;
    }
}

// ---------------------------------------------------------------------------
// FUSED Phase A: per 64-edge tile: msg GEMM (MFMA, W in regs, inputs staged
// in XOR-swizzled LDS) -> msg tile to LDS -> in-block per-node mean finish.
// Interior nodes: direct f32 mean row write. Boundary nodes: atomic partials
// (pre-divided by full count). 3 barriers / tile.
// ---------------------------------------------------------------------------
__global__ __launch_bounds__(256, 3) void msg_fused_kernel(
    const unsigned short* __restrict__ nodeB, const int* __restrict__ srcS,
    const int* __restrict__ perm, const int* __restrict__ dstS,
    const float* __restrict__ edge_emb, const unsigned short* __restrict__ WtM,
    const float* __restrict__ b_msg, const int* __restrict__ base,
    const int* __restrict__ cnt, float* __restrict__ mean)
{
    __shared__ unsigned short sIn[TILE][192];    // 24576 B; 16B chunks XOR row&7
    __shared__ unsigned short sMsg[TILE][128];   // 16384 B; 8B chunks XOR row&7

    const int lane = threadIdx.x & 63;
    const int wav  = threadIdx.x >> 6;
    const int j = lane & 15;
    const int q = lane >> 4;

    // W slice (out rows 32*wav .. 32*wav+31) in registers
    frag8 wfr[2][6];
#pragma unroll
    for (int m2 = 0; m2 < 2; ++m2) {
        const unsigned short* wrow = WtM + ((wav * 2 + m2) * 16 + j) * K1;
#pragma unroll
        for (int kc = 0; kc < 6; ++kc)
            wfr[m2][kc] = *(const frag8*)&wrow[(kc * 4 + q) * 8];
    }
    float bias[2][4];
#pragma unroll
    for (int m2 = 0; m2 < 2; ++m2)
#pragma unroll
        for (int r = 0; r < 4; ++r) bias[m2][r] = b_msg[(wav * 2 + m2) * 16 + q * 4 + r];

    // staging role: thread t covers edge row eL = t>>2, quarter qt = t&3
    const int eL = threadIdx.x >> 2;
    const int qt = threadIdx.x & 3;
    const int swz = eL & 7;

    uint4  nst[4];    // node part: 64B bf16
    float4 est[4];    // edge part: 64B f32

    const int t0 = blockIdx.x;

    // prologue: issue loads for tile t0
    {
        const int e = t0 * TILE + eL;
        const int sp = min(max(srcS[e], 0), N_NODES - 1);
        const unsigned short* nrow = nodeB + (size_t)sp * D_NODE + qt * 32;
#pragma unroll
        for (int i = 0; i < 4; ++i) nst[i] = *(const uint4*)&nrow[i * 8];
        const float* erow = edge_emb + (size_t)perm[e] * D_EDGE + qt * 16;
#pragma unroll
        for (int i = 0; i < 4; ++i) est[i] = *(const float4*)&erow[i * 4];
    }

#pragma unroll 1
    for (int t = t0; t < NT; t += gridDim.x) {
        const int e0 = t * TILE;

        __syncthreads();   // (a) prior GEMM + reduction done; sIn free

        // write staged tile into sIn (XOR-swizzled 16B chunks)
        {
            unsigned short* drow = &sIn[eL][0];
#pragma unroll
            for (int i = 0; i < 4; ++i)
                *(uint4*)&drow[((4 * qt + i) ^ swz) * 8] = nst[i];
#pragma unroll
            for (int h = 0; h < 2; ++h) {
                F8 u;
                u.f = pack8(est[h * 2], est[h * 2 + 1]);
                *(uint4*)&drow[((16 + 2 * qt + h) ^ swz) * 8] = u.u4;
            }
        }
        __syncthreads();   // (b) sIn ready

        // issue next tile's loads early (latency hides under compute)
        const int tn = t + gridDim.x;
        if (tn < NT) {
            const int e = tn * TILE + eL;
            const int sp = min(max(srcS[e], 0), N_NODES - 1);
            const unsigned short* nrow = nodeB + (size_t)sp * D_NODE + qt * 32;
#pragma unroll
            for (int i = 0; i < 4; ++i) nst[i] = *(const uint4*)&nrow[i * 8];
            const float* erow = edge_emb + (size_t)perm[e] * D_EDGE + qt * 16;
#pragma unroll
            for (int i = 0; i < 4; ++i) est[i] = *(const float4*)&erow[i * 4];
        }

        // GEMM: wave computes outs 32*wav..+31 for all 64 edges
        facc acc[2][4];
#pragma unroll
        for (int m2 = 0; m2 < 2; ++m2)
#pragma unroll
            for (int eg = 0; eg < 4; ++eg) { facc z = {0.f,0.f,0.f,0.f}; acc[m2][eg] = z; }

        const int rsw = j & 7;
#pragma unroll
        for (int eg = 0; eg < 4; ++eg) {
            const unsigned short* irow = &sIn[eg * 16 + j][0];
#pragma unroll
            for (int kc = 0; kc < 6; ++kc) {
                frag8 b = *(const frag8*)&irow[((4 * kc + q) ^ rsw) * 8];
                acc[0][eg] = __builtin_amdgcn_mfma_f32_16x16x32_bf16(wfr[0][kc], b, acc[0][eg], 0, 0, 0);
                acc[1][eg] = __builtin_amdgcn_mfma_f32_16x16x32_bf16(wfr[1][kc], b, acc[1][eg], 0, 0, 0);
            }
        }

        // epilogue: bias+relu+cvt bf16 -> sMsg (8B chunks XOR row&7)
#pragma unroll
        for (int eg = 0; eg < 4; ++eg) {
            unsigned short* mrow = &sMsg[eg * 16 + j][0];
#pragma unroll
            for (int m2 = 0; m2 < 2; ++m2) {
                float v0 = fmaxf(acc[m2][eg][0] + bias[m2][0], 0.f);
                float v1 = fmaxf(acc[m2][eg][1] + bias[m2][1], 0.f);
                float v2 = fmaxf(acc[m2][eg][2] + bias[m2][2], 0.f);
                float v3 = fmaxf(acc[m2][eg][3] + bias[m2][3], 0.f);
                uint2 w;
                w.x = (unsigned)f2bf(v0) | ((unsigned)f2bf(v1) << 16);
                w.y = (unsigned)f2bf(v2) | ((unsigned)f2bf(v3) << 16);
                int c64 = wav * 8 + m2 * 4 + q;        // u64 index 0..31
                *(uint2*)&mrow[(c64 ^ rsw) * 4] = w;
            }
        }
        __syncthreads();   // (c) sMsg ready

        // in-block mean finish: wave handles nodes d_lo+wav, +4, ...
        const int d_lo = dstS[e0];
        const int d_hi = dstS[e0 + TILE - 1];
        for (int n = d_lo + wav; n <= d_hi; n += 4) {
            const int b = base[n];
            const int c = cnt[n];
            const int lo = max(b - e0, 0);
            const int hi = min(b + c - e0, TILE);
            float s0 = 0.f, s1 = 0.f;
            for (int r = lo; r < hi; ++r) {
                const unsigned* mr = (const unsigned*)&sMsg[r][0];
                unsigned u = mr[(((lane >> 1) ^ (r & 7)) << 1) | (lane & 1)];
                s0 += bflo(u); s1 += bfhi(u);
            }
            const float inv = 1.0f / fmaxf((float)c, 1.0f);
            s0 *= inv; s1 *= inv;
            float* mp = mean + (size_t)n * D_MSG + lane * 2;
            if (b >= e0 && b + c <= e0 + TILE) {
                *(float2*)mp = make_float2(s0, s1);      // interior: exclusive
            } else {
                atomicAdd(mp + 0, s0);                   // boundary partial
                atomicAdd(mp + 1, s1);
            }
        }
    }
}

// ---------------------------------------------------------------------------
// Phase C: node GEMM. nodeB bf16 fragments + mean f32 (packed on the fly).
// ---------------------------------------------------------------------------
__global__ __launch_bounds__(256) void node_gemm_kernel(
    const unsigned short* __restrict__ nodeB, const float* __restrict__ mean,
    const unsigned short* __restrict__ WtU, const float* __restrict__ b_upd,
    float* __restrict__ out)
{
    __shared__ unsigned short sW[128 * K2];   // 65536 B

    for (int idx = threadIdx.x; idx < 128 * 32; idx += 256) {
        int o = idx >> 5, ch = idx & 31;
        *(uint4*)&sW[o * K2 + (ch ^ (o & 7)) * 8] = *(const uint4*)&WtU[o * K2 + ch * 8];
    }

    const int lane = threadIdx.x & 63;
    const int wav  = threadIdx.x >> 6;
    const int j = lane & 15;
    const int q = lane >> 4;
    const int rs = j & 7;

    float bias[32];
#pragma unroll
    for (int mt = 0; mt < 8; ++mt)
#pragma unroll
        for (int r = 0; r < 4; ++r) bias[mt * 4 + r] = b_upd[mt * 16 + q * 4 + r];
    __syncthreads();

    const int n0w = blockIdx.x * 256 + wav * 64;

#pragma unroll 1
    for (int g = 0; g < 4; ++g) {
        const int n = n0w + g * 16 + j;
        const bool valid = (n < N_NODES);
        const size_t nn = valid ? (size_t)n : 0;

        frag8 bfr[8];
        const unsigned short* nrow = nodeB + nn * D_NODE;
#pragma unroll
        for (int kc = 0; kc < 4; ++kc)
            bfr[kc] = *(const frag8*)&nrow[kc * 32 + q * 8];
        const float* mrow = mean + nn * D_MSG;
#pragma unroll
        for (int kc = 0; kc < 4; ++kc) {
            float4 a = *(const float4*)&mrow[kc * 32 + q * 8];
            float4 c = *(const float4*)&mrow[kc * 32 + q * 8 + 4];
            bfr[4 + kc] = pack8(a, c);
        }

        facc acc[8];
#pragma unroll
        for (int mt = 0; mt < 8; ++mt) { facc z = {0.f, 0.f, 0.f, 0.f}; acc[mt] = z; }

#pragma unroll
        for (int mt = 0; mt < 8; ++mt) {
            const unsigned short* wrow = &sW[(mt * 16 + j) * K2];
#pragma unroll
            for (int kc = 0; kc < 8; ++kc) {
                frag8 a = *(const frag8*)&wrow[((kc * 4 + q) ^ rs) * 8];
                acc[mt] = __builtin_amdgcn_mfma_f32_16x16x32_bf16(a, bfr[kc], acc[mt], 0, 0, 0);
            }
        }

        if (valid) {
            float* orow = out + (size_t)n * D_OUT;
#pragma unroll
            for (int mt = 0; mt < 8; ++mt)
#pragma unroll
                for (int r = 0; r < 4; ++r)
                    orow[mt * 16 + q * 4 + r] = fmaxf(acc[mt][r] + bias[mt * 4 + r], 0.f);
        }
    }
}

// ===========================================================================
// FALLBACK PATH (round-3): fused msg+aggregate if ws too small.
// ===========================================================================
__global__ __launch_bounds__(256) void msg_agg_kernel_fb(
    const float* __restrict__ node_emb, const int* __restrict__ src,
    const float* __restrict__ edge_emb, const unsigned short* __restrict__ WtM,
    const float* __restrict__ b_msg, const int* __restrict__ perm,
    const int* __restrict__ dstS, const int* __restrict__ cnt,
    float* __restrict__ mean)
{
    __shared__ unsigned short sW[128 * K1];

    for (int idx = threadIdx.x; idx < 128 * 24; idx += 256) {
        int o = idx / 24, ch = idx % 24;
        *(uint4*)&sW[o * K1 + (ch ^ (o & 7)) * 8] = *(const uint4*)&WtM[o * K1 + ch * 8];
    }

    const int lane = threadIdx.x & 63;
    const int wav  = threadIdx.x >> 6;
    const int j = lane & 15;
    const int q = lane >> 4;

    float bias[32];
#pragma unroll
    for (int mt = 0; mt < 8; ++mt)
#pragma unroll
        for (int r = 0; r < 4; ++r) bias[mt * 4 + r] = b_msg[mt * 16 + q * 4 + r];
    __syncthreads();

    const int e0w = blockIdx.x * 256 + wav * 64;
    float carry[32];
    int carry_d = -1;

#pragma unroll 1
    for (int g = 0; g < 4; ++g) {
        const int e = e0w + g * 16 + j;
        const int p = perm[e];
        const int d = dstS[e];
        const int sp = min(max(src[p], 0), N_NODES - 1);
        const float invc = 1.0f / (float)cnt[d];

        frag8 bfr[6];
        const float* nrow = node_emb + (size_t)sp * D_NODE;
#pragma unroll
        for (int kc = 0; kc < 4; ++kc) {
            float4 a = *(const float4*)&nrow[kc * 32 + q * 8];
            float4 c = *(const float4*)&nrow[kc * 32 + q * 8 + 4];
            bfr[kc] = pack8(a, c);
        }
        const float* erow = edge_emb + (size_t)p * D_EDGE;
#pragma unroll
        for (int kc = 0; kc < 2; ++kc) {
            float4 a = *(const float4*)&erow[kc * 32 + q * 8];
            float4 c = *(const float4*)&erow[kc * 32 + q * 8 + 4];
            bfr[4 + kc] = pack8(a, c);
        }

        facc acc[8];
#pragma unroll
        for (int mt = 0; mt < 8; ++mt) { facc z = {0.f, 0.f, 0.f, 0.f}; acc[mt] = z; }

#pragma unroll
        for (int mt = 0; mt < 8; ++mt) {
            const unsigned short* wrow = &sW[(mt * 16 + j) * K1];
            const int rs = j & 7;
#pragma unroll
            for (int kc = 0; kc < 6; ++kc) {
                frag8 a = *(const frag8*)&wrow[((kc * 4 + q) ^ rs) * 8];
                acc[mt] = __builtin_amdgcn_mfma_f32_16x16x32_bf16(a, bfr[kc], acc[mt], 0, 0, 0);
            }
        }

        float v[32];
#pragma unroll
        for (int mt = 0; mt < 8; ++mt)
#pragma unroll
            for (int r = 0; r < 4; ++r) {
                float t = acc[mt][r] + bias[mt * 4 + r];
                v[mt * 4 + r] = fmaxf(t, 0.f) * invc;
            }

        int dprev = __shfl_up(d, 1, 16);
        int head = (j == 0 || d != dprev) ? 1 : 0;
        int seg = head;
#pragma unroll
        for (int s = 1; s < 16; s <<= 1) { int t = __shfl_up(seg, s, 16); if (j >= s) seg += t; }
        int sg1 = __shfl_up(seg, 1, 16);
        int sg2 = __shfl_up(seg, 2, 16);
        int sg4 = __shfl_up(seg, 4, 16);
        int sg8 = __shfl_up(seg, 8, 16);
        bool ok1 = (j >= 1) && (sg1 == seg);
        bool ok2 = (j >= 2) && (sg2 == seg);
        bool ok4 = (j >= 4) && (sg4 == seg);
        bool ok8 = (j >= 8) && (sg8 == seg);

#pragma unroll
        for (int i = 0; i < 32; ++i) { float t = __shfl_up(v[i], 1, 16); if (ok1) v[i] += t; }
#pragma unroll
        for (int i = 0; i < 32; ++i) { float t = __shfl_up(v[i], 2, 16); if (ok2) v[i] += t; }
#pragma unroll
        for (int i = 0; i < 32; ++i) { float t = __shfl_up(v[i], 4, 16); if (ok4) v[i] += t; }
#pragma unroll
        for (int i = 0; i < 32; ++i) { float t = __shfl_up(v[i], 8, 16); if (ok8) v[i] += t; }

        int d0 = __shfl(d, 0, 16);
        if (g > 0) {
            if (d0 != carry_d) {
                if (j == 0) {
                    float* mrow = mean + (size_t)carry_d * D_MSG;
#pragma unroll
                    for (int mt = 0; mt < 8; ++mt)
#pragma unroll
                        for (int r = 0; r < 4; ++r)
                            atomicAdd(&mrow[mt * 16 + q * 4 + r], carry[mt * 4 + r]);
                }
            } else if (seg == 1) {
#pragma unroll
                for (int i = 0; i < 32; ++i) v[i] += carry[i];
            }
        }

#pragma unroll
        for (int i = 0; i < 32; ++i) carry[i] = __shfl(v[i], 15, 16);
        carry_d = __shfl(d, 15, 16);

        int dnext = __shfl_down(d, 1, 16);
        bool tail = (j < 15) ? (dnext != d) : (g == 3);
        if (tail) {
            float* mrow = mean + (size_t)d * D_MSG;
#pragma unroll
            for (int mt = 0; mt < 8; ++mt)
#pragma unroll
                for (int r = 0; r < 4; ++r)
                    atomicAdd(&mrow[mt * 16 + q * 4 + r], v[mt * 4 + r]);
        }
    }
}

__global__ __launch_bounds__(256) void node_kernel_fb(
    const float* __restrict__ node_emb, const float* __restrict__ mean,
    const unsigned short* __restrict__ WtU, const float* __restrict__ b_upd,
    float* __restrict__ out)
{
    __shared__ unsigned short sW[128 * K2];

    for (int idx = threadIdx.x; idx < 128 * 32; idx += 256) {
        int o = idx >> 5, ch = idx & 31;
        *(uint4*)&sW[o * K2 + (ch ^ (o & 7)) * 8] = *(const uint4*)&WtU[o * K2 + ch * 8];
    }

    const int lane = threadIdx.x & 63;
    const int wav  = threadIdx.x >> 6;
    const int j = lane & 15;
    const int q = lane >> 4;

    float bias[32];
#pragma unroll
    for (int mt = 0; mt < 8; ++mt)
#pragma unroll
        for (int r = 0; r < 4; ++r) bias[mt * 4 + r] = b_upd[mt * 16 + q * 4 + r];
    __syncthreads();

    const int n0w = blockIdx.x * 256 + wav * 64;

#pragma unroll 1
    for (int g = 0; g < 4; ++g) {
        const int n = n0w + g * 16 + j;
        const bool valid = (n < N_NODES);
        const size_t nn = valid ? (size_t)n : 0;

        frag8 bfr[8];
        const float* nrow = node_emb + nn * D_NODE;
#pragma unroll
        for (int kc = 0; kc < 4; ++kc) {
            float4 a = *(const float4*)&nrow[kc * 32 + q * 8];
            float4 c = *(const float4*)&nrow[kc * 32 + q * 8 + 4];
            bfr[kc] = pack8(a, c);
        }
        const float* mrow = mean + nn * D_MSG;
#pragma unroll
        for (int kc = 0; kc < 4; ++kc) {
            float4 a = *(const float4*)&mrow[kc * 32 + q * 8];
            float4 c = *(const float4*)&mrow[kc * 32 + q * 8 + 4];
            bfr[4 + kc] = pack8(a, c);
        }

        facc acc[8];
#pragma unroll
        for (int mt = 0; mt < 8; ++mt) { facc z = {0.f, 0.f, 0.f, 0.f}; acc[mt] = z; }

#pragma unroll
        for (int mt = 0; mt < 8; ++mt) {
            const unsigned short* wrow = &sW[(mt * 16 + j) * K2];
            const int rs = j & 7;
#pragma unroll
            for (int kc = 0; kc < 8; ++kc) {
                frag8 a = *(const frag8*)&wrow[((kc * 4 + q) ^ rs) * 8];
                acc[mt] = __builtin_amdgcn_mfma_f32_16x16x32_bf16(a, bfr[kc], acc[mt], 0, 0, 0);
            }
        }

        if (valid) {
            float* orow = out + (size_t)n * D_OUT;
#pragma unroll
            for (int mt = 0; mt < 8; ++mt)
#pragma unroll
                for (int r = 0; r < 4; ++r)
                    orow[mt * 16 + q * 4 + r] = fmaxf(acc[mt][r] + bias[mt * 4 + r], 0.f);
        }
    }
}

extern "C" void kernel_launch(void* const* d_in, const int* in_sizes, int n_in,
                              void* d_out, int out_size, void* d_ws, size_t ws_size,
                              hipStream_t stream) {
    const float* node_emb = (const float*)d_in[0];
    const int*   edge_idx = (const int*)d_in[1];
    const float* edge_emb = (const float*)d_in[2];
    const float* W_msg    = (const float*)d_in[3];
    const float* b_msg    = (const float*)d_in[4];
    const float* W_upd    = (const float*)d_in[5];
    const float* b_upd    = (const float*)d_in[6];
    float* out = (float*)d_out;

    const int* src = edge_idx;
    const int* dst = edge_idx + N_EDGES;

    char* W = (char*)d_ws;

    if (ws_size >= 97315200ULL) {
        // ---- FAST PATH (fused mean) ----
        float* mean  = (float*)(W + 0);                           // 51,200,000
        int* cnt     = (int*)(W + 51200000);                      //    400,000
        int* cursor  = (int*)(W + 51600000);                      //    400,000
        int* base    = (int*)(W + 52000000);                      //    400,000
        int* part    = (int*)(W + 52400000);                      //        512
        int* perm    = (int*)(W + 52400512);                      //  6,400,000
        int* srcS    = (int*)(W + 58800512);                      //  6,400,000
        int* dstS    = (int*)(W + 65200512);                      //  6,400,000
        unsigned short* WtM   = (unsigned short*)(W + 71600512);  //     49,152
        unsigned short* WtU   = (unsigned short*)(W + 71649664);  //     65,536
        unsigned short* nodeB = (unsigned short*)(W + 71715200);  // 25,600,000

        hipMemsetAsync(d_ws, 0, 52000000, stream);   // mean + cnt + cursor

        prep_w_kernel<<<224, 256, 0, stream>>>(W_msg, W_upd, WtM, WtU);
        prep_node_kernel<<<2048, 256, 0, stream>>>(node_emb, (unsigned int*)nodeB);
        hist_kernel<<<1024, 256, 0, stream>>>(dst, cnt);
        scan_blocks<<<NSB, 1024, 0, stream>>>(cnt, base, part);
        scan_partials<<<1, 128, 0, stream>>>(part);
        scan_add<<<NSB, 1024, 0, stream>>>(base, part);
        scatter_kernel<<<1024, 256, 0, stream>>>(dst, src, base, cursor, perm, srcS, dstS);
        msg_fused_kernel<<<2048, 256, 0, stream>>>(nodeB, srcS, perm, dstS, edge_emb,
                                                   WtM, b_msg, base, cnt, mean);
        node_gemm_kernel<<<391, 256, 0, stream>>>(nodeB, mean, WtU, b_upd, out);
    } else {
        // ---- FALLBACK (round-3 layout & kernels) ----
        float* mean  = (float*)W;                               // 51,200,000
        int* cnt     = (int*)(W + 51200000);
        int* cursor  = (int*)(W + 51600000);
        int* base    = (int*)(W + 52000000);
        int* part    = (int*)(W + 52400000);
        int* perm    = (int*)(W + 52400512);
        int* dstS    = (int*)(W + 58800512);
        int* srcS    = (int*)(W + 65200512);
        unsigned short* WtM = (unsigned short*)(W + 71600512);
        unsigned short* WtU = (unsigned short*)(W + 71649664);

        hipMemsetAsync(d_ws, 0, 52000000, stream);

        prep_w_kernel<<<224, 256, 0, stream>>>(W_msg, W_upd, WtM, WtU);
        hist_kernel<<<1024, 256, 0, stream>>>(dst, cnt);
        scan_blocks<<<NSB, 1024, 0, stream>>>(cnt, base, part);
        scan_partials<<<1, 128, 0, stream>>>(part);
        scan_add<<<NSB, 1024, 0, stream>>>(base, part);
        scatter_kernel<<<1024, 256, 0, stream>>>(dst, src, base, cursor, perm, srcS, dstS);
        msg_agg_kernel_fb<<<6250, 256, 0, stream>>>(node_emb, src, edge_emb, WtM,
                                                    b_msg, perm, dstS, cnt, mean);
        node_kernel_fb<<<391, 256, 0, stream>>>(node_emb, mean, WtU, b_upd, out);
    }
}